// Round 13
// baseline (140.503 us; speedup 1.0000x reference)
//
#include <hip/hip_runtime.h>
#include <hip/hip_bf16.h>
#include <math.h>

#define NRES 512
#define CS   384
#define CZ   128
#define NH   12
#define PW   1152   // packed projection width
#define JB   64     // j per flash block
#define NCH  8      // chunks = NRES/JB
#define PSTRIDE32 1040  // part chunk stride in u32 units
#define KS   6      // k_out K splits (2112 = 6*352)
#define KAW  352    // Kfull row width (11 * 32)
#define BFW  4224   // Bfull row group: 12*352

static constexpr float WL_F      = 0.57735026918962576f;   // sqrt(1/3)
static constexpr float HALF_WC_F = 0.11785113019775792f;   // 0.5*sqrt(2/(9*4))

typedef __attribute__((ext_vector_type(8))) short short8v;
typedef __attribute__((ext_vector_type(4))) float floatx4;

__device__ __forceinline__ ushort f2b(float f) {
    union { float f; uint u; } v; v.f = f;
    return (ushort)((v.u + 0x7FFFu + ((v.u >> 16) & 1u)) >> 16);
}
__device__ __forceinline__ float b2f(ushort b) {
    union { uint u; float f; } v; v.u = ((uint)b) << 16; return v.f;
}

// ---------------------------------------------------------------------------
// Kernel 0: merged prep. blocks [0,384): pack Wcat rows (+wbt16 on block 0);
// blocks [384,582): Wout -> WoutT16 bf16 transpose tiles (33 x 6).
// ---------------------------------------------------------------------------
__global__ __launch_bounds__(256) void k_prep(
    const float* __restrict__ Wq, const float* __restrict__ Wk,
    const float* __restrict__ Wv, const float* __restrict__ Wqp,
    const float* __restrict__ Wkp, const float* __restrict__ Wvp,
    const float* __restrict__ Wb, const float* __restrict__ Wout,
    float* __restrict__ Wcat, ushort* __restrict__ wbt16,
    ushort* __restrict__ woT)
{
    __shared__ ushort tile[64][72];
    const int bx = blockIdx.x;
    if (bx < 384) {
        const int c = bx;
        for (int col = threadIdx.x; col < PW; col += 256) {
            float v;
            if (col < 192)      v = Wq [(size_t)c * 192 + col];
            else if (col < 384) v = Wk [(size_t)c * 192 + col - 192];
            else if (col < 576) v = Wv [(size_t)c * 192 + col - 384];
            else if (col < 720) v = Wqp[(size_t)c * 144 + col - 576];
            else if (col < 864) v = Wkp[(size_t)c * 144 + col - 720];
            else                v = Wvp[(size_t)c * 288 + col - 864];
            Wcat[(size_t)c * PW + col] = v;
        }
        if (bx == 0) {
            for (int idx = threadIdx.x; idx < 16 * 128; idx += 256) {
                const int h = idx >> 7, cc = idx & 127;
                wbt16[idx] = (h < NH) ? f2b(WL_F * Wb[(size_t)cc * NH + h]) : (ushort)0;
            }
        }
    } else {
        const int t = bx - 384;
        const int k0 = (t % 33) * 64, c0 = (t / 33) * 64;
        for (int idx = threadIdx.x; idx < 4096; idx += 256) {
            const int r = idx >> 6, c = idx & 63;
            tile[r][c] = f2b(Wout[(size_t)(k0 + r) * 384 + c0 + c]);
        }
        __syncthreads();
        for (int idx = threadIdx.x; idx < 4096; idx += 256) {
            const int c = idx >> 6, r = idx & 63;
            woT[(size_t)(c0 + c) * 2112 + k0 + r] = tile[r][c];
        }
    }
}

// ---------------------------------------------------------------------------
// Kernel 1: P[512][1152] = s @ Wcat, rigid transform fused for cols >= 576.
// ---------------------------------------------------------------------------
__global__ __launch_bounds__(256) void k_gemm(
    const float* __restrict__ s, const float* __restrict__ Wcat,
    const float* __restrict__ rots, const float* __restrict__ trans,
    float* __restrict__ P)
{
    const int tid = threadIdx.x;
    const int tx = tid & 15, ty = tid >> 4;
    const int n0 = blockIdx.x * 48;
    const int m0 = blockIdx.y * 32;
    __shared__ float As[32][34];
    __shared__ float Bs[32][50];
    __shared__ float rot_lds[32][12];

    if (n0 >= 576) {
        for (int idx = tid; idx < 32 * 12; idx += 256) {
            int r = idx / 12, q = idx % 12;
            rot_lds[r][q] = (q < 9) ? rots[(size_t)(m0 + r) * 9 + q]
                                    : trans[(size_t)(m0 + r) * 3 + q - 9];
        }
    }

    float acc[2][3];
    #pragma unroll
    for (int u = 0; u < 2; ++u)
        #pragma unroll
        for (int v = 0; v < 3; ++v) acc[u][v] = 0.f;

    for (int k0 = 0; k0 < CS; k0 += 32) {
        __syncthreads();
        #pragma unroll
        for (int l = 0; l < 4; ++l) {
            int idx = tid + l * 256;
            int kk = idx & 31, r = idx >> 5;
            As[kk][r] = s[(size_t)(m0 + r) * CS + k0 + kk];
        }
        #pragma unroll
        for (int l = 0; l < 6; ++l) {
            int idx = tid + l * 256;
            int kk = idx / 48, cc = idx % 48;
            Bs[kk][cc] = Wcat[(size_t)(k0 + kk) * PW + n0 + cc];
        }
        __syncthreads();
        #pragma unroll
        for (int kk = 0; kk < 32; ++kk) {
            const float2 a = *(const float2*)&As[kk][ty * 2];
            const float b0 = Bs[kk][tx * 3], b1 = Bs[kk][tx * 3 + 1], b2 = Bs[kk][tx * 3 + 2];
            acc[0][0] += a.x * b0; acc[0][1] += a.x * b1; acc[0][2] += a.x * b2;
            acc[1][0] += a.y * b0; acc[1][1] += a.y * b1; acc[1][2] += a.y * b2;
        }
    }

    #pragma unroll
    for (int u = 0; u < 2; ++u) {
        float v0 = acc[u][0], v1 = acc[u][1], v2 = acc[u][2];
        if (n0 >= 576) {
            const float* RT = rot_lds[ty * 2 + u];
            const float p0 = v0, p1 = v1, p2 = v2;
            v0 = RT[0] * p0 + RT[1] * p1 + RT[2] * p2 + RT[9];
            v1 = RT[3] * p0 + RT[4] * p1 + RT[5] * p2 + RT[10];
            v2 = RT[6] * p0 + RT[7] * p1 + RT[8] * p2 + RT[11];
        }
        float* dst = P + (size_t)(m0 + ty * 2 + u) * PW + n0 + tx * 3;
        dst[0] = v0; dst[1] = v1; dst[2] = v2;
    }
}

// ---------------------------------------------------------------------------
// Kernel 1b: per row r emit Kfull[r][352] (K-side bf16), Bfull[r][12][352]
// (Q-side logit B-matrix bf16), and vp[120][512][4] bf16 (V repack: group
// g = 4 consecutive vh/vg cols, j-major -> phase-E loads 2 j per 16 B).
// Kfull: [0,192) k | [192,336) kg | [336,348) nj_h | 348: 1 | 349-351: 0
// ---------------------------------------------------------------------------
__global__ __launch_bounds__(128) void k_ka(
    const float* __restrict__ P, const float* __restrict__ gamma,
    ushort* __restrict__ Kfull, ushort* __restrict__ Bfull,
    ushort* __restrict__ vp)
{
    const int r = blockIdx.x;
    const int tid = threadIdx.x;
    __shared__ float njs[NH];   // |kg|^2
    __shared__ float nqs[NH];   // |qg|^2
    const float* prow = P + (size_t)r * PW;
    const float* kr   = prow + 192;
    const float* vr   = prow + 384;
    const float* qgr  = prow + 576;
    const float* kgr  = prow + 720;
    const float* vgr  = prow + 864;
    if (tid < NH) {
        float s = 0.f, sq = 0.f;
        #pragma unroll
        for (int e = 0; e < 12; ++e) {
            const float v = kgr[tid * 12 + e];  s += v * v;
            const float q = qgr[tid * 12 + e];  sq += q * q;
        }
        njs[tid] = s; nqs[tid] = sq;
    }
    __syncthreads();
    ushort* dst = Kfull + (size_t)r * KAW;
    for (int t = tid; t < KAW; t += 128) {
        float v;
        if (t < 192)       v = kr[t];
        else if (t < 336)  v = kgr[t - 192];
        else if (t < 348)  v = njs[t - 336];
        else if (t == 348) v = 1.0f;
        else               v = 0.f;
        dst[t] = f2b(v);
    }
    ushort* bd = Bfull + (size_t)r * BFW;
    for (int t = tid; t < BFW; t += 128) {
        const int h = t / 352, k = t - h * 352;
        float v = 0.f;
        if (k < 192) {
            if ((k >> 4) == h) v = 0.25f * WL_F * prow[k];
        } else if (k < 336) {
            const int e = k - 192;
            if (e / 12 == h) v = 2.f * HALF_WC_F * WL_F * gamma[h] * qgr[e];
        } else if (k < 348) {
            if (k - 336 == h) v = -HALF_WC_F * WL_F * gamma[h];
        } else if (k == 348) {
            v = -HALF_WC_F * WL_F * gamma[h] * nqs[h];
        }
        bd[t] = f2b(v);
    }
    for (int t = tid; t < 480; t += 128) {
        const int g = t >> 2, e = t & 3;
        const float v = (g < 48) ? vr[g * 4 + e] : vgr[(g - 48) * 4 + e];
        vp[((size_t)g * 512 + r) * 4 + e] = f2b(v);
    }
}

// ---------------------------------------------------------------------------
// Kernel 2: MFMA flash chunk. grid (512 i, 8 jc), 256 threads (4 waves).
// LDS ~25 KB -> 6 blocks/CU. z read ONCE (A-frags in regs + zbT scatter).
// BfT COPIED from global Bfull (528 uint4) into LDS, padded stride 360
// (bank spread); logits = 15-step MFMA chain; softmax; o_hat MFMA; o/o_hp
// from packed bf16 vp (16 x 16B loads/thread, 2 j per load, unroll 8).
// uni overlay: BfT [0,8640) while logits; then ltf [0,3264) | ltb
// [3264,5312) | halfacc [5312,9152). 5 barriers.
// part chunk (u32 stride 1040): u16[0,1536) ohat | [1536,1728) o |
// [1728,2016) ohp ; f32 @u32 1008+h = pm, 1020+h = ps.
// ---------------------------------------------------------------------------
__global__ __launch_bounds__(256, 6) void k_flash(
    const float* __restrict__ z, const ushort* __restrict__ wbt16,
    const ushort* __restrict__ Kfull, const ushort* __restrict__ Bfull,
    const ushort* __restrict__ vp, uint* __restrict__ part)
{
    const int i   = blockIdx.x;
    const int jc  = blockIdx.y;
    const int j0  = jc * JB;
    const int tid = threadIdx.x;
    const int wid = tid >> 6, lane = tid & 63;

    __shared__ __align__(16) short zbT[128 * JB];    // 16384 B
    __shared__ __align__(16) char  uni[9152];

    short*  BfT     = (short*)uni;                   // [12][360] (logits phase)
    float*  ltf     = (float*)uni;                   // [12][68]  (after)
    short*  ltb     = (short*)(uni + 3264);          // [16][64]
    float4* halfacc = (float4*)(uni + 5312);         // [240]

    uint* pb32   = part + ((size_t)i * NCH + jc) * PSTRIDE32;
    ushort* pb16 = (ushort*)pb32;
    float* pbf   = (float*)pb32;

    const int jb = wid * 16 + (lane & 15);           // this thread's j row
    const int ko = (lane >> 4) * 8;                  // channel octet base

    // ---- phase A: z load (once) -> A-frags in regs + zbT scatter; BfT copy ----
    short8v af[4];
    {
        const float* za = z + ((size_t)i * NRES + j0 + jb) * CZ + ko;
        #pragma unroll
        for (int m = 0; m < 4; ++m) {
            const float4 f0 = *(const float4*)(za + m * 32);
            const float4 f1 = *(const float4*)(za + m * 32 + 4);
            short8v a;
            a[0] = (short)f2b(f0.x); a[1] = (short)f2b(f0.y);
            a[2] = (short)f2b(f0.z); a[3] = (short)f2b(f0.w);
            a[4] = (short)f2b(f1.x); a[5] = (short)f2b(f1.y);
            a[6] = (short)f2b(f1.z); a[7] = (short)f2b(f1.w);
            af[m] = a;
            #pragma unroll
            for (int e = 0; e < 8; ++e) {
                const int c = ko + m * 32 + e;
                zbT[c * 64 + (((jb >> 3) ^ (c & 7)) * 8) + (jb & 7)] = a[e];
            }
        }
        // copy Bfull[i] (12 rows x 44 uint4) -> BfT padded stride 360
        const uint4* bsrc = (const uint4*)(Bfull + (size_t)i * BFW);
        for (int idx = tid; idx < 528; idx += 256) {
            const int r = idx / 44, c = idx % 44;
            *(uint4*)&BfT[r * 360 + c * 8] = bsrc[idx];
        }
    }
    __syncthreads();   // barrier 1: zbT + BfT ready

    // ---- phase B: fused logits MFMA (15 K-steps) ----
    floatx4 lacc = {0.f, 0.f, 0.f, 0.f};
    {
        const int n  = lane & 15;
        const int nb = (n < NH) ? n : 0;             // clamp garbage cols
        const ushort* arow = Kfull + (size_t)(j0 + jb) * KAW + ko;
        const short*  brow = &BfT[nb * 360 + ko];
        const ushort* wrow = wbt16 + n * 128 + ko;
        #pragma unroll
        for (int st = 0; st < 11; ++st) {
            const short8v a = *(const short8v*)(arow + st * 32);
            const short8v b = *(const short8v*)(brow + st * 32);
            lacc = __builtin_amdgcn_mfma_f32_16x16x32_bf16(a, b, lacc, 0, 0, 0);
        }
        #pragma unroll
        for (int st = 0; st < 4; ++st) {
            const short8v b = *(const short8v*)(wrow + st * 32);
            lacc = __builtin_amdgcn_mfma_f32_16x16x32_bf16(af[st], b, lacc, 0, 0, 0);
        }
    }
    __syncthreads();   // barrier 2: all waves done reading BfT
    {
        const int n = lane & 15;
        if (n < NH) {
            #pragma unroll
            for (int r = 0; r < 4; ++r)
                ltf[n * 68 + wid * 16 + (lane >> 4) * 4 + r] = lacc[r];
        }
    }
    __syncthreads();   // barrier 3: ltf ready

    // ---- phase C: chunk softmax (16 lanes/head); pm/ps direct to global ----
    if (tid < 192) {
        const int h = tid >> 4, s = tid & 15;
        float4 v = *(const float4*)&ltf[h * 68 + s * 4];
        float m = fmaxf(fmaxf(v.x, v.y), fmaxf(v.z, v.w));
        #pragma unroll
        for (int o = 1; o < 16; o <<= 1) m = fmaxf(m, __shfl_xor(m, o));
        float4 e;
        e.x = __expf(v.x - m); e.y = __expf(v.y - m);
        e.z = __expf(v.z - m); e.w = __expf(v.w - m);
        float sum = e.x + e.y + e.z + e.w;
        #pragma unroll
        for (int o = 1; o < 16; o <<= 1) sum += __shfl_xor(sum, o);
        *(float4*)&ltf[h * 68 + s * 4] = e;
        const uint lo = (uint)f2b(e.x) | ((uint)f2b(e.y) << 16);
        const uint hi = (uint)f2b(e.z) | ((uint)f2b(e.w) << 16);
        uint* dst = (uint*)&ltb[h * 64 + (((s >> 1) ^ (h & 7)) * 8) + (s & 1) * 4];
        dst[0] = lo; dst[1] = hi;
        if (s == 0) { pbf[1008 + h] = m; pbf[1020 + h] = sum; }
    } else {
        const int tt = tid - 192;
        uint* dst = (uint*)&ltb[(12 + (tt >> 4)) * 64 + (tt & 15) * 4];
        dst[0] = 0u; dst[1] = 0u;
    }
    __syncthreads();   // barrier 4: ltb + e(ltf) ready

    // ---- phase D: o_hat MFMA — all 4 waves, 2 N-tiles each ----
    {
        const int hrow = lane & 15;
        const int u0 = (lane >> 4), u1 = u0 + 4;
        const short8v a0 = *(const short8v*)&ltb[hrow * 64 + ((u0 ^ (hrow & 7)) * 8)];
        const short8v a1 = *(const short8v*)&ltb[hrow * 64 + ((u1 ^ (hrow & 7)) * 8)];
        #pragma unroll
        for (int t = 0; t < 2; ++t) {
            const int d = (wid * 2 + t) * 16 + (lane & 15);
            const short8v b0 = *(const short8v*)&zbT[d * 64 + ((u0 ^ (d & 7)) * 8)];
            const short8v b1 = *(const short8v*)&zbT[d * 64 + ((u1 ^ (d & 7)) * 8)];
            floatx4 acc = {0.f, 0.f, 0.f, 0.f};
            acc = __builtin_amdgcn_mfma_f32_16x16x32_bf16(a0, b0, acc, 0, 0, 0);
            acc = __builtin_amdgcn_mfma_f32_16x16x32_bf16(a1, b1, acc, 0, 0, 0);
            #pragma unroll
            for (int r = 0; r < 4; ++r) {
                const int h = u0 * 4 + r;
                if (h < NH) pb16[h * 128 + d] = f2b(acc[r]);
            }
        }
    }

    // ---- phase E: o / o_hp — 240 slots, packed bf16 vp, 2 j per 16B load ----
    {
        if (tid < 240) {
            const int half = tid / 120, col = tid % 120;
            const int h = (col < 48) ? (col >> 2) : ((col - 48) / 6);
            const ushort* vb = vp + ((size_t)col * 512 + j0 + half * 32) * 4;
            const float* er = &ltf[h * 68 + half * 32];
            float ax = 0.f, ay = 0.f, az = 0.f, aw = 0.f;
            #pragma unroll 8
            for (int t = 0; t < 16; ++t) {
                const uint4 raw = *(const uint4*)(vb + t * 8);
                const float e0 = er[2 * t], e1 = er[2 * t + 1];
                ax += e0 * b2f((ushort)raw.x)         + e1 * b2f((ushort)raw.z);
                ay += e0 * b2f((ushort)(raw.x >> 16)) + e1 * b2f((ushort)(raw.z >> 16));
                az += e0 * b2f((ushort)raw.y)         + e1 * b2f((ushort)raw.w);
                aw += e0 * b2f((ushort)(raw.y >> 16)) + e1 * b2f((ushort)(raw.w >> 16));
            }
            halfacc[tid] = make_float4(ax, ay, az, aw);
        }
        __syncthreads();   // barrier 5: halfacc ready
        if (tid < 120) {
            const float4 s0 = halfacc[tid], s1 = halfacc[tid + 120];
            const int off16 = (tid < 48) ? 1536 + tid * 4 : 1728 + (tid - 48) * 4;
            uint* dst = (uint*)&pb16[off16];
            dst[0] = (uint)f2b(s0.x + s1.x) | ((uint)f2b(s0.y + s1.y) << 16);
            dst[1] = (uint)f2b(s0.z + s1.z) | ((uint)f2b(s0.w + s1.w) << 16);
        }
    }
}

// ---------------------------------------------------------------------------
// Kernel 3: combine 8 chunks -> cat16 row (bf16). grid 512, 256 threads.
// ---------------------------------------------------------------------------
__global__ __launch_bounds__(256) void k_combine(
    const uint* __restrict__ part, const float* __restrict__ rots,
    const float* __restrict__ trans, ushort* __restrict__ cat16)
{
    const int i   = blockIdx.x;
    const int tid = threadIdx.x;
    __shared__ float wgt[NCH][NH];
    __shared__ float ohp[288];

    const uint* base = part + (size_t)i * NCH * PSTRIDE32;
    if (tid < NH) {
        const int h = tid;
        float mm[NCH];
        float M = -1e30f;
        #pragma unroll
        for (int c = 0; c < NCH; ++c) {
            mm[c] = ((const float*)(base + c * PSTRIDE32))[1008 + h];
            M = fmaxf(M, mm[c]);
        }
        float S = 0.f;
        #pragma unroll
        for (int c = 0; c < NCH; ++c) {
            const float w = __expf(mm[c] - M);
            S += w * ((const float*)(base + c * PSTRIDE32))[1020 + h];
            wgt[c][h] = w;
        }
        const float inv = 1.0f / S;
        #pragma unroll
        for (int c = 0; c < NCH; ++c) wgt[c][h] *= inv;
    }
    __syncthreads();

    ushort* crow = cat16 + (size_t)i * 2112;
    uint*   crowu = (uint*)crow;
    for (int idx2 = tid; idx2 < 768; idx2 += 256) {
        const int h = idx2 >> 6;
        float v0 = 0.f, v1 = 0.f;
        #pragma unroll
        for (int c = 0; c < NCH; ++c) {
            const uint u = base[c * PSTRIDE32 + idx2];
            const float w = wgt[c][h];
            v0 += b2f((ushort)u) * w;
            v1 += b2f((ushort)(u >> 16)) * w;
        }
        crowu[idx2] = (uint)f2b(v0) | ((uint)f2b(v1) << 16);
    }
    if (tid < 96) {
        const int h = tid >> 3;
        float v0 = 0.f, v1 = 0.f;
        #pragma unroll
        for (int c = 0; c < NCH; ++c) {
            const uint u = base[c * PSTRIDE32 + 768 + tid];
            const float w = wgt[c][h];
            v0 += b2f((ushort)u) * w;
            v1 += b2f((ushort)(u >> 16)) * w;
        }
        crowu[768 + tid] = (uint)f2b(v0) | ((uint)f2b(v1) << 16);
    }
    if (tid < 144) {
        const int h = tid / 12;
        float v0 = 0.f, v1 = 0.f;
        #pragma unroll
        for (int c = 0; c < NCH; ++c) {
            const uint u = base[c * PSTRIDE32 + 864 + tid];
            const float w = wgt[c][h];
            v0 += b2f((ushort)u) * w;
            v1 += b2f((ushort)(u >> 16)) * w;
        }
        ohp[tid * 2] = v0; ohp[tid * 2 + 1] = v1;
    }
    __syncthreads();

    if (tid < 96) {
        const int h = tid >> 3, p = tid & 7;
        float R[9];
        #pragma unroll
        for (int k = 0; k < 9; ++k) R[k] = rots[(size_t)i * 9 + k];
        const float g0 = ohp[h * 24 + p * 3 + 0] - trans[(size_t)i * 3 + 0];
        const float g1 = ohp[h * 24 + p * 3 + 1] - trans[(size_t)i * 3 + 1];
        const float g2 = ohp[h * 24 + p * 3 + 2] - trans[(size_t)i * 3 + 2];
        const float oy0 = R[0] * g0 + R[3] * g1 + R[6] * g2;
        const float oy1 = R[1] * g0 + R[4] * g1 + R[7] * g2;
        const float oy2 = R[2] * g0 + R[5] * g1 + R[8] * g2;
        crow[1728 + h * 24 + p * 3 + 0] = f2b(oy0);
        crow[1728 + h * 24 + p * 3 + 1] = f2b(oy1);
        crow[1728 + h * 24 + p * 3 + 2] = f2b(oy2);
        crow[2016 + h * 8 + p] = f2b(sqrtf(oy0 * oy0 + oy1 * oy1 + oy2 * oy2));
    }
}

// ---------------------------------------------------------------------------
// Kernel 4: out-proj MFMA. grid (16 m, 12 n, 6 k). 4 waves = 2x2 16x16 tiles.
// ---------------------------------------------------------------------------
__global__ __launch_bounds__(256) void k_out(
    const ushort* __restrict__ cat16, const ushort* __restrict__ woT,
    float* __restrict__ opart)
{
    const int tid = threadIdx.x;
    const int wid = tid >> 6, lane = tid & 63;
    const int wm = wid >> 1, wn = wid & 1;
    const int i0 = blockIdx.x * 32 + wm * 16;
    const int c0 = blockIdx.y * 32 + wn * 16;
    const int k0 = blockIdx.z * 352;
    const ushort* arow = cat16 + (size_t)(i0 + (lane & 15)) * 2112 + k0 + (lane >> 4) * 8;
    const ushort* brow = woT   + (size_t)(c0 + (lane & 15)) * 2112 + k0 + (lane >> 4) * 8;
    floatx4 acc = {0.f, 0.f, 0.f, 0.f};
    #pragma unroll
    for (int st = 0; st < 11; ++st) {
        const short8v a = *(const short8v*)(arow + st * 32);
        const short8v b = *(const short8v*)(brow + st * 32);
        acc = __builtin_amdgcn_mfma_f32_16x16x32_bf16(a, b, acc, 0, 0, 0);
    }
    float* ob = opart + (size_t)blockIdx.z * 512 * 384;
    #pragma unroll
    for (int r = 0; r < 4; ++r) {
        const int i = i0 + (lane >> 4) * 4 + r;
        ob[(size_t)i * 384 + c0 + (lane & 15)] = acc[r];
    }
}

// Kernel 5: reduce 6 k-partials + bias.
__global__ __launch_bounds__(256) void k_outred(
    const float* __restrict__ opart, const float* __restrict__ bout,
    float* __restrict__ out)
{
    const int e4 = blockIdx.x * 256 + threadIdx.x;
    const float4* p = (const float4*)opart;
    const float4 b = ((const float4*)bout)[e4 % 96];
    float4 r = b;
    #pragma unroll
    for (int k = 0; k < KS; ++k) {
        const float4 v = p[e4 + k * 49152];
        r.x += v.x; r.y += v.y; r.z += v.z; r.w += v.w;
    }
    ((float4*)out)[e4] = r;
}

// ---------------------------------------------------------------------------
extern "C" void kernel_launch(void* const* d_in, const int* in_sizes, int n_in,
                              void* d_out, int out_size, void* d_ws, size_t ws_size,
                              hipStream_t stream)
{
    const float* s_i   = (const float*)d_in[0];
    const float* z_ij  = (const float*)d_in[1];
    const float* rots  = (const float*)d_in[2];
    const float* trans = (const float*)d_in[3];
    const float* Wq    = (const float*)d_in[4];
    const float* Wk    = (const float*)d_in[5];
    const float* Wv    = (const float*)d_in[6];
    const float* Wqp   = (const float*)d_in[7];
    const float* Wkp   = (const float*)d_in[8];
    const float* Wvp   = (const float*)d_in[9];
    const float* Wb    = (const float*)d_in[10];
    const float* gamma = (const float*)d_in[11];
    const float* Wout  = (const float*)d_in[12];
    const float* bout  = (const float*)d_in[13];
    float* ws = (float*)d_ws;
    float*  wcat  = ws;                          // 442368 f
    float*  P     = ws + 442368;                 // 589824 f
    uint*   part  = (uint*)(P + 589824);         // 512*8*1040 u32 (17 MB)
    float*  opart = (float*)part;                // aliased (sequenced)
    // big region: Bfull (k_ka -> k_flash) THEN cat16 (k_combine -> k_out).
    ushort* bfull = (ushort*)(part + (size_t)512 * NCH * PSTRIDE32);  // 512*4224 u16
    ushort* cat16 = bfull;                       // overlay (disjoint lifetime)
    ushort* wbt16 = bfull + (size_t)512 * BFW;   // 2048 u16
    ushort* kfull = wbt16 + 2048;                // 512*352 u16
    ushort* woT   = kfull + 512 * KAW;           // 384*2112 u16
    ushort* vp    = woT + (size_t)384 * 2112;    // 120*512*4 u16
    float*  out   = (float*)d_out;

    hipLaunchKernelGGL(k_prep, dim3(582), dim3(256), 0, stream,
                       Wq, Wk, Wv, Wqp, Wkp, Wvp, Wb, Wout, wcat, wbt16, woT);
    hipLaunchKernelGGL(k_gemm, dim3(24, 16), dim3(256), 0, stream,
                       s_i, wcat, rots, trans, P);
    hipLaunchKernelGGL(k_ka, dim3(512), dim3(128), 0, stream,
                       P, gamma, kfull, bfull, vp);
    hipLaunchKernelGGL(k_flash, dim3(512, NCH), dim3(256), 0, stream,
                       z_ij, wbt16, kfull, bfull, vp, part);
    hipLaunchKernelGGL(k_combine, dim3(512), dim3(256), 0, stream,
                       part, rots, trans, cat16);
    hipLaunchKernelGGL(k_out, dim3(16, 12, KS), dim3(256), 0, stream,
                       cat16, woT, opart);
    hipLaunchKernelGGL(k_outred, dim3(192), dim3(256), 0, stream,
                       opart, bout, out);
}

// Round 14
// 124.065 us; speedup vs baseline: 1.1325x; 1.1325x over previous
//
#include <hip/hip_runtime.h>
#include <hip/hip_bf16.h>
#include <math.h>

#define NRES 512
#define CS   384
#define CZ   128
#define NH   12
#define PW   1152   // packed projection width
#define JB   64     // j per flash block
#define NCH  8      // chunks = NRES/JB
#define PSTRIDE32 1040  // part chunk stride in u32 units
#define KS   6      // k_out K splits (2112 = 6*352)
#define KAW  352    // Kfull row width (11 * 32)

static constexpr float WL_F      = 0.57735026918962576f;   // sqrt(1/3)
static constexpr float HALF_WC_F = 0.11785113019775792f;   // 0.5*sqrt(2/(9*4))

typedef __attribute__((ext_vector_type(8))) short short8v;
typedef __attribute__((ext_vector_type(4))) float floatx4;

__device__ __forceinline__ ushort f2b(float f) {
    union { float f; uint u; } v; v.f = f;
    return (ushort)((v.u + 0x7FFFu + ((v.u >> 16) & 1u)) >> 16);
}
__device__ __forceinline__ float b2f(ushort b) {
    union { uint u; float f; } v; v.u = ((uint)b) << 16; return v.f;
}

// ---------------------------------------------------------------------------
// Kernel 0: merged prep. blocks [0,384): pack Wcat rows (+wbt16 on block 0);
// blocks [384,582): Wout -> WoutT16 bf16 transpose tiles (33 x 6).
// ---------------------------------------------------------------------------
__global__ __launch_bounds__(256) void k_prep(
    const float* __restrict__ Wq, const float* __restrict__ Wk,
    const float* __restrict__ Wv, const float* __restrict__ Wqp,
    const float* __restrict__ Wkp, const float* __restrict__ Wvp,
    const float* __restrict__ Wb, const float* __restrict__ Wout,
    float* __restrict__ Wcat, ushort* __restrict__ wbt16,
    ushort* __restrict__ woT)
{
    __shared__ ushort tile[64][72];
    const int bx = blockIdx.x;
    if (bx < 384) {
        const int c = bx;
        for (int col = threadIdx.x; col < PW; col += 256) {
            float v;
            if (col < 192)      v = Wq [(size_t)c * 192 + col];
            else if (col < 384) v = Wk [(size_t)c * 192 + col - 192];
            else if (col < 576) v = Wv [(size_t)c * 192 + col - 384];
            else if (col < 720) v = Wqp[(size_t)c * 144 + col - 576];
            else if (col < 864) v = Wkp[(size_t)c * 144 + col - 720];
            else                v = Wvp[(size_t)c * 288 + col - 864];
            Wcat[(size_t)c * PW + col] = v;
        }
        if (bx == 0) {
            for (int idx = threadIdx.x; idx < 16 * 128; idx += 256) {
                const int h = idx >> 7, cc = idx & 127;
                wbt16[idx] = (h < NH) ? f2b(WL_F * Wb[(size_t)cc * NH + h]) : (ushort)0;
            }
        }
    } else {
        const int t = bx - 384;
        const int k0 = (t % 33) * 64, c0 = (t / 33) * 64;
        for (int idx = threadIdx.x; idx < 4096; idx += 256) {
            const int r = idx >> 6, c = idx & 63;
            tile[r][c] = f2b(Wout[(size_t)(k0 + r) * 384 + c0 + c]);
        }
        __syncthreads();
        for (int idx = threadIdx.x; idx < 4096; idx += 256) {
            const int c = idx >> 6, r = idx & 63;
            woT[(size_t)(c0 + c) * 2112 + k0 + r] = tile[r][c];
        }
    }
}

// ---------------------------------------------------------------------------
// Kernel 1: P[512][1152] = s @ Wcat, rigid transform fused for cols >= 576.
// ---------------------------------------------------------------------------
__global__ __launch_bounds__(256) void k_gemm(
    const float* __restrict__ s, const float* __restrict__ Wcat,
    const float* __restrict__ rots, const float* __restrict__ trans,
    float* __restrict__ P)
{
    const int tid = threadIdx.x;
    const int tx = tid & 15, ty = tid >> 4;
    const int n0 = blockIdx.x * 48;
    const int m0 = blockIdx.y * 32;
    __shared__ float As[32][34];
    __shared__ float Bs[32][50];
    __shared__ float rot_lds[32][12];

    if (n0 >= 576) {
        for (int idx = tid; idx < 32 * 12; idx += 256) {
            int r = idx / 12, q = idx % 12;
            rot_lds[r][q] = (q < 9) ? rots[(size_t)(m0 + r) * 9 + q]
                                    : trans[(size_t)(m0 + r) * 3 + q - 9];
        }
    }

    float acc[2][3];
    #pragma unroll
    for (int u = 0; u < 2; ++u)
        #pragma unroll
        for (int v = 0; v < 3; ++v) acc[u][v] = 0.f;

    for (int k0 = 0; k0 < CS; k0 += 32) {
        __syncthreads();
        #pragma unroll
        for (int l = 0; l < 4; ++l) {
            int idx = tid + l * 256;
            int kk = idx & 31, r = idx >> 5;
            As[kk][r] = s[(size_t)(m0 + r) * CS + k0 + kk];
        }
        #pragma unroll
        for (int l = 0; l < 6; ++l) {
            int idx = tid + l * 256;
            int kk = idx / 48, cc = idx % 48;
            Bs[kk][cc] = Wcat[(size_t)(k0 + kk) * PW + n0 + cc];
        }
        __syncthreads();
        #pragma unroll
        for (int kk = 0; kk < 32; ++kk) {
            const float2 a = *(const float2*)&As[kk][ty * 2];
            const float b0 = Bs[kk][tx * 3], b1 = Bs[kk][tx * 3 + 1], b2 = Bs[kk][tx * 3 + 2];
            acc[0][0] += a.x * b0; acc[0][1] += a.x * b1; acc[0][2] += a.x * b2;
            acc[1][0] += a.y * b0; acc[1][1] += a.y * b1; acc[1][2] += a.y * b2;
        }
    }

    #pragma unroll
    for (int u = 0; u < 2; ++u) {
        float v0 = acc[u][0], v1 = acc[u][1], v2 = acc[u][2];
        if (n0 >= 576) {
            const float* RT = rot_lds[ty * 2 + u];
            const float p0 = v0, p1 = v1, p2 = v2;
            v0 = RT[0] * p0 + RT[1] * p1 + RT[2] * p2 + RT[9];
            v1 = RT[3] * p0 + RT[4] * p1 + RT[5] * p2 + RT[10];
            v2 = RT[6] * p0 + RT[7] * p1 + RT[8] * p2 + RT[11];
        }
        float* dst = P + (size_t)(m0 + ty * 2 + u) * PW + n0 + tx * 3;
        dst[0] = v0; dst[1] = v1; dst[2] = v2;
    }
}

// ---------------------------------------------------------------------------
// Kernel 1b: Kfull[512][352] bf16 augmented K rows + vp2 packed V.
// Kfull: [0,192) k | [192,336) kg | [336,348) nj_h | 348: 1 | 349-351: 0
// vp2[p][c][par] bf16 (p=j/2, c in [0,480): 192 vh | 288 vg, par=j&1):
// one 16B load in k_flash phase E = cols c..c+3 x 2 consecutive j, and
// consecutive threads (c+4) read consecutive 16B (coalesced).
// ---------------------------------------------------------------------------
__global__ __launch_bounds__(128) void k_ka(
    const float* __restrict__ P, ushort* __restrict__ Kfull,
    ushort* __restrict__ vp2)
{
    const int j = blockIdx.x;
    const int tid = threadIdx.x;
    __shared__ float njs[NH];
    const float* prow = P + (size_t)j * PW;
    const float* kr  = prow + 192;
    const float* vr  = prow + 384;
    const float* kgr = prow + 720;
    const float* vgr = prow + 864;
    if (tid < NH) {
        float s = 0.f;
        #pragma unroll
        for (int e = 0; e < 12; ++e) { const float v = kgr[tid * 12 + e]; s += v * v; }
        njs[tid] = s;
    }
    __syncthreads();
    ushort* dst = Kfull + (size_t)j * KAW;
    for (int t = tid; t < KAW; t += 128) {
        float v;
        if (t < 192)       v = kr[t];
        else if (t < 336)  v = kgr[t - 192];
        else if (t < 348)  v = njs[t - 336];
        else if (t == 348) v = 1.0f;
        else               v = 0.f;
        dst[t] = f2b(v);
    }
    const int p = j >> 1, par = j & 1;
    for (int c = tid; c < 480; c += 128) {
        const float v = (c < 192) ? vr[c] : vgr[c - 192];
        vp2[((size_t)p * 480 + c) * 2 + par] = f2b(v);
    }
}

// ---------------------------------------------------------------------------
// Kernel 2: MFMA flash chunk. grid (512 i, 8 jc), 256 threads (4 waves).
// R11-proven structure: z read ONCE (A-frags in regs + zbT scatter); BfT
// built in LDS single-pass; wbt16 B-frags from global; logits = 15-step
// MFMA chain; softmax; o_hat MFMA; o/o_hp from packed bf16 vp2
// (16 x 16B coalesced loads/thread, 2 j per load).
// uni overlay: BfT [12][352] while logits; then ltf [16][68] | ltb | halfacc.
// part chunk (u32 stride 1040): u16[0,1536) ohat | [1536,1728) o |
// [1728,2016) ohp ; f32 @u32 1008+h = pm, 1020+h = ps.
// ---------------------------------------------------------------------------
__global__ __launch_bounds__(256, 6) void k_flash(
    const float* __restrict__ z, const ushort* __restrict__ wbt16,
    const float* __restrict__ gamma, const float* __restrict__ P,
    const ushort* __restrict__ Kfull, const ushort* __restrict__ vp2,
    uint* __restrict__ part)
{
    const int i   = blockIdx.x;
    const int jc  = blockIdx.y;
    const int j0  = jc * JB;
    const int tid = threadIdx.x;
    const int wid = tid >> 6, lane = tid & 63;

    __shared__ __align__(16) short zbT[128 * JB];    // 16384 B
    __shared__ __align__(16) char  uni[10240];       // BfT | {ltf, ltb, halfacc}
    __shared__ float pm[NH], ps[NH];

    short*  BfT     = (short*)uni;                   // [12][352] (logits phase)
    float*  ltf     = (float*)uni;                   // [16][68]  (after)
    short*  ltb     = (short*)(uni + 4352);          // [16][64]
    float4* halfacc = (float4*)(uni + 6400);         // [240]

    uint* pb32   = part + ((size_t)i * NCH + jc) * PSTRIDE32;
    ushort* pb16 = (ushort*)pb32;
    float* pbf   = (float*)pb32;

    const int jb = wid * 16 + (lane & 15);           // this thread's j row
    const int ko = (lane >> 4) * 8;                  // channel octet base

    // ---- phase A: z load (once) -> A-frags in regs + zbT scatter; BfT build ----
    short8v af[4];
    {
        const float* za = z + ((size_t)i * NRES + j0 + jb) * CZ + ko;
        #pragma unroll
        for (int m = 0; m < 4; ++m) {
            const float4 f0 = *(const float4*)(za + m * 32);
            const float4 f1 = *(const float4*)(za + m * 32 + 4);
            short8v a;
            a[0] = (short)f2b(f0.x); a[1] = (short)f2b(f0.y);
            a[2] = (short)f2b(f0.z); a[3] = (short)f2b(f0.w);
            a[4] = (short)f2b(f1.x); a[5] = (short)f2b(f1.y);
            a[6] = (short)f2b(f1.z); a[7] = (short)f2b(f1.w);
            af[m] = a;
            #pragma unroll
            for (int e = 0; e < 8; ++e) {
                const int c = ko + m * 32 + e;
                zbT[c * 64 + (((jb >> 3) ^ (c & 7)) * 8) + (jb & 7)] = a[e];
            }
        }
    }
    {
        const float* prow = P + (size_t)i * PW;
        for (int t = tid; t < 12 * 352; t += 256) {
            const int h = t / 352, k = t - h * 352;
            float v = 0.f;
            if (k < 192) {
                if ((k >> 4) == h) v = 0.25f * WL_F * prow[k];
            } else if (k < 336) {
                const int e = k - 192;
                if (e / 12 == h) v = 2.f * HALF_WC_F * WL_F * gamma[h] * prow[576 + e];
            } else if (k < 348) {
                if (k - 336 == h) v = -HALF_WC_F * WL_F * gamma[h];
            } else if (k == 348) {
                float ss = 0.f;
                #pragma unroll
                for (int e = 0; e < 12; ++e) {
                    const float x = prow[576 + h * 12 + e];
                    ss += x * x;
                }
                v = -HALF_WC_F * WL_F * gamma[h] * ss;
            }
            BfT[t] = (short)f2b(v);
        }
    }
    __syncthreads();

    // ---- phase B: fused logits MFMA (15 K-steps) ----
    floatx4 lacc = {0.f, 0.f, 0.f, 0.f};
    {
        const int n  = lane & 15;
        const int nb = (n < NH) ? n : 0;             // clamp garbage cols
        const ushort* arow = Kfull + (size_t)(j0 + jb) * KAW + ko;
        const short*  brow = &BfT[nb * 352 + ko];
        const ushort* wrow = wbt16 + n * 128 + ko;
        #pragma unroll
        for (int st = 0; st < 11; ++st) {
            const short8v a = *(const short8v*)(arow + st * 32);
            const short8v b = *(const short8v*)(brow + st * 32);
            lacc = __builtin_amdgcn_mfma_f32_16x16x32_bf16(a, b, lacc, 0, 0, 0);
        }
        #pragma unroll
        for (int st = 0; st < 4; ++st) {
            const short8v b = *(const short8v*)(wrow + st * 32);
            lacc = __builtin_amdgcn_mfma_f32_16x16x32_bf16(af[st], b, lacc, 0, 0, 0);
        }
    }
    __syncthreads();   // all waves done reading BfT
    {
        const int n = lane & 15;
        #pragma unroll
        for (int r = 0; r < 4; ++r)
            ltf[n * 68 + wid * 16 + (lane >> 4) * 4 + r] = lacc[r];
    }
    __syncthreads();

    // ---- phase C: chunk softmax (16 lanes/head) ----
    if (tid < 192) {
        const int h = tid >> 4, s = tid & 15;
        float4 v = *(const float4*)&ltf[h * 68 + s * 4];
        float m = fmaxf(fmaxf(v.x, v.y), fmaxf(v.z, v.w));
        #pragma unroll
        for (int o = 1; o < 16; o <<= 1) m = fmaxf(m, __shfl_xor(m, o));
        float4 e;
        e.x = __expf(v.x - m); e.y = __expf(v.y - m);
        e.z = __expf(v.z - m); e.w = __expf(v.w - m);
        float sum = e.x + e.y + e.z + e.w;
        #pragma unroll
        for (int o = 1; o < 16; o <<= 1) sum += __shfl_xor(sum, o);
        *(float4*)&ltf[h * 68 + s * 4] = e;
        const uint lo = (uint)f2b(e.x) | ((uint)f2b(e.y) << 16);
        const uint hi = (uint)f2b(e.z) | ((uint)f2b(e.w) << 16);
        uint* dst = (uint*)&ltb[h * 64 + (((s >> 1) ^ (h & 7)) * 8) + (s & 1) * 4];
        dst[0] = lo; dst[1] = hi;
        if (s == 0) { pm[h] = m; ps[h] = sum; }
    } else {
        const int tt = tid - 192;
        uint* dst = (uint*)&ltb[(12 + (tt >> 4)) * 64 + (tt & 15) * 4];
        dst[0] = 0u; dst[1] = 0u;
    }
    __syncthreads();

    // ---- phase D: o_hat MFMA — all 4 waves, 2 N-tiles each ----
    {
        const int hrow = lane & 15;
        const int u0 = (lane >> 4), u1 = u0 + 4;
        const short8v a0 = *(const short8v*)&ltb[hrow * 64 + ((u0 ^ (hrow & 7)) * 8)];
        const short8v a1 = *(const short8v*)&ltb[hrow * 64 + ((u1 ^ (hrow & 7)) * 8)];
        #pragma unroll
        for (int t = 0; t < 2; ++t) {
            const int d = (wid * 2 + t) * 16 + (lane & 15);
            const short8v b0 = *(const short8v*)&zbT[d * 64 + ((u0 ^ (d & 7)) * 8)];
            const short8v b1 = *(const short8v*)&zbT[d * 64 + ((u1 ^ (d & 7)) * 8)];
            floatx4 acc = {0.f, 0.f, 0.f, 0.f};
            acc = __builtin_amdgcn_mfma_f32_16x16x32_bf16(a0, b0, acc, 0, 0, 0);
            acc = __builtin_amdgcn_mfma_f32_16x16x32_bf16(a1, b1, acc, 0, 0, 0);
            #pragma unroll
            for (int r = 0; r < 4; ++r) {
                const int h = u0 * 4 + r;
                if (h < NH) pb16[h * 128 + d] = f2b(acc[r]);
            }
        }
    }

    // ---- phase E: o / o_hp — 240 slots, vp2 packed (2 j per 16B, coalesced) ----
    {
        if (tid < 240) {
            const int half = tid / 120, col = tid % 120;
            const int h = (col < 48) ? (col >> 2) : ((col - 48) / 6);
            const ushort* vb = vp2 + ((size_t)((j0 >> 1) + half * 16) * 480 + col * 4) * 2;
            const float* er = &ltf[h * 68 + half * 32];
            float ax = 0.f, ay = 0.f, az = 0.f, aw = 0.f;
            #pragma unroll 8
            for (int t = 0; t < 16; ++t) {
                const uint4 raw = *(const uint4*)(vb + (size_t)t * 960);
                const float e0 = er[2 * t], e1 = er[2 * t + 1];
                ax += e0 * b2f((ushort)raw.x) + e1 * b2f((ushort)(raw.x >> 16));
                ay += e0 * b2f((ushort)raw.y) + e1 * b2f((ushort)(raw.y >> 16));
                az += e0 * b2f((ushort)raw.z) + e1 * b2f((ushort)(raw.z >> 16));
                aw += e0 * b2f((ushort)raw.w) + e1 * b2f((ushort)(raw.w >> 16));
            }
            halfacc[tid] = make_float4(ax, ay, az, aw);
        }
        __syncthreads();
        if (tid < 120) {
            const float4 s0 = halfacc[tid], s1 = halfacc[tid + 120];
            const int off16 = (tid < 48) ? 1536 + tid * 4 : 1728 + (tid - 48) * 4;
            uint* dst = (uint*)&pb16[off16];
            dst[0] = (uint)f2b(s0.x + s1.x) | ((uint)f2b(s0.y + s1.y) << 16);
            dst[1] = (uint)f2b(s0.z + s1.z) | ((uint)f2b(s0.w + s1.w) << 16);
        }
        if (tid < NH) { pbf[1008 + tid] = pm[tid]; pbf[1020 + tid] = ps[tid]; }
    }
}

// ---------------------------------------------------------------------------
// Kernel 3: combine 8 chunks -> cat16 row (bf16). grid 512, 256 threads.
// ---------------------------------------------------------------------------
__global__ __launch_bounds__(256) void k_combine(
    const uint* __restrict__ part, const float* __restrict__ rots,
    const float* __restrict__ trans, ushort* __restrict__ cat16)
{
    const int i   = blockIdx.x;
    const int tid = threadIdx.x;
    __shared__ float wgt[NCH][NH];
    __shared__ float ohp[288];

    const uint* base = part + (size_t)i * NCH * PSTRIDE32;
    if (tid < NH) {
        const int h = tid;
        float mm[NCH];
        float M = -1e30f;
        #pragma unroll
        for (int c = 0; c < NCH; ++c) {
            mm[c] = ((const float*)(base + c * PSTRIDE32))[1008 + h];
            M = fmaxf(M, mm[c]);
        }
        float S = 0.f;
        #pragma unroll
        for (int c = 0; c < NCH; ++c) {
            const float w = __expf(mm[c] - M);
            S += w * ((const float*)(base + c * PSTRIDE32))[1020 + h];
            wgt[c][h] = w;
        }
        const float inv = 1.0f / S;
        #pragma unroll
        for (int c = 0; c < NCH; ++c) wgt[c][h] *= inv;
    }
    __syncthreads();

    ushort* crow = cat16 + (size_t)i * 2112;
    uint*   crowu = (uint*)crow;
    for (int idx2 = tid; idx2 < 768; idx2 += 256) {
        const int h = idx2 >> 6;
        float v0 = 0.f, v1 = 0.f;
        #pragma unroll
        for (int c = 0; c < NCH; ++c) {
            const uint u = base[c * PSTRIDE32 + idx2];
            const float w = wgt[c][h];
            v0 += b2f((ushort)u) * w;
            v1 += b2f((ushort)(u >> 16)) * w;
        }
        crowu[idx2] = (uint)f2b(v0) | ((uint)f2b(v1) << 16);
    }
    if (tid < 96) {
        const int h = tid >> 3;
        float v0 = 0.f, v1 = 0.f;
        #pragma unroll
        for (int c = 0; c < NCH; ++c) {
            const uint u = base[c * PSTRIDE32 + 768 + tid];
            const float w = wgt[c][h];
            v0 += b2f((ushort)u) * w;
            v1 += b2f((ushort)(u >> 16)) * w;
        }
        crowu[768 + tid] = (uint)f2b(v0) | ((uint)f2b(v1) << 16);
    }
    if (tid < 144) {
        const int h = tid / 12;
        float v0 = 0.f, v1 = 0.f;
        #pragma unroll
        for (int c = 0; c < NCH; ++c) {
            const uint u = base[c * PSTRIDE32 + 864 + tid];
            const float w = wgt[c][h];
            v0 += b2f((ushort)u) * w;
            v1 += b2f((ushort)(u >> 16)) * w;
        }
        ohp[tid * 2] = v0; ohp[tid * 2 + 1] = v1;
    }
    __syncthreads();

    if (tid < 96) {
        const int h = tid >> 3, p = tid & 7;
        float R[9];
        #pragma unroll
        for (int k = 0; k < 9; ++k) R[k] = rots[(size_t)i * 9 + k];
        const float g0 = ohp[h * 24 + p * 3 + 0] - trans[(size_t)i * 3 + 0];
        const float g1 = ohp[h * 24 + p * 3 + 1] - trans[(size_t)i * 3 + 1];
        const float g2 = ohp[h * 24 + p * 3 + 2] - trans[(size_t)i * 3 + 2];
        const float oy0 = R[0] * g0 + R[3] * g1 + R[6] * g2;
        const float oy1 = R[1] * g0 + R[4] * g1 + R[7] * g2;
        const float oy2 = R[2] * g0 + R[5] * g1 + R[8] * g2;
        crow[1728 + h * 24 + p * 3 + 0] = f2b(oy0);
        crow[1728 + h * 24 + p * 3 + 1] = f2b(oy1);
        crow[1728 + h * 24 + p * 3 + 2] = f2b(oy2);
        crow[2016 + h * 8 + p] = f2b(sqrtf(oy0 * oy0 + oy1 * oy1 + oy2 * oy2));
    }
}

// ---------------------------------------------------------------------------
// Kernel 4: out-proj MFMA. grid (16 m, 12 n, 6 k). 4 waves = 2x2 16x16 tiles.
// ---------------------------------------------------------------------------
__global__ __launch_bounds__(256) void k_out(
    const ushort* __restrict__ cat16, const ushort* __restrict__ woT,
    float* __restrict__ opart)
{
    const int tid = threadIdx.x;
    const int wid = tid >> 6, lane = tid & 63;
    const int wm = wid >> 1, wn = wid & 1;
    const int i0 = blockIdx.x * 32 + wm * 16;
    const int c0 = blockIdx.y * 32 + wn * 16;
    const int k0 = blockIdx.z * 352;
    const ushort* arow = cat16 + (size_t)(i0 + (lane & 15)) * 2112 + k0 + (lane >> 4) * 8;
    const ushort* brow = woT   + (size_t)(c0 + (lane & 15)) * 2112 + k0 + (lane >> 4) * 8;
    floatx4 acc = {0.f, 0.f, 0.f, 0.f};
    #pragma unroll
    for (int st = 0; st < 11; ++st) {
        const short8v a = *(const short8v*)(arow + st * 32);
        const short8v b = *(const short8v*)(brow + st * 32);
        acc = __builtin_amdgcn_mfma_f32_16x16x32_bf16(a, b, acc, 0, 0, 0);
    }
    float* ob = opart + (size_t)blockIdx.z * 512 * 384;
    #pragma unroll
    for (int r = 0; r < 4; ++r) {
        const int i = i0 + (lane >> 4) * 4 + r;
        ob[(size_t)i * 384 + c0 + (lane & 15)] = acc[r];
    }
}

// Kernel 5: reduce 6 k-partials + bias.
__global__ __launch_bounds__(256) void k_outred(
    const float* __restrict__ opart, const float* __restrict__ bout,
    float* __restrict__ out)
{
    const int e4 = blockIdx.x * 256 + threadIdx.x;
    const float4* p = (const float4*)opart;
    const float4 b = ((const float4*)bout)[e4 % 96];
    float4 r = b;
    #pragma unroll
    for (int k = 0; k < KS; ++k) {
        const float4 v = p[e4 + k * 49152];
        r.x += v.x; r.y += v.y; r.z += v.z; r.w += v.w;
    }
    ((float4*)out)[e4] = r;
}

// ---------------------------------------------------------------------------
extern "C" void kernel_launch(void* const* d_in, const int* in_sizes, int n_in,
                              void* d_out, int out_size, void* d_ws, size_t ws_size,
                              hipStream_t stream)
{
    const float* s_i   = (const float*)d_in[0];
    const float* z_ij  = (const float*)d_in[1];
    const float* rots  = (const float*)d_in[2];
    const float* trans = (const float*)d_in[3];
    const float* Wq    = (const float*)d_in[4];
    const float* Wk    = (const float*)d_in[5];
    const float* Wv    = (const float*)d_in[6];
    const float* Wqp   = (const float*)d_in[7];
    const float* Wkp   = (const float*)d_in[8];
    const float* Wvp   = (const float*)d_in[9];
    const float* Wb    = (const float*)d_in[10];
    const float* gamma = (const float*)d_in[11];
    const float* Wout  = (const float*)d_in[12];
    const float* bout  = (const float*)d_in[13];
    float* ws = (float*)d_ws;
    float*  wcat  = ws;                          // 442368 f
    float*  P     = ws + 442368;                 // 589824 f
    uint*   part  = (uint*)(P + 589824);         // 512*8*1040 u32 (17 MB)
    float*  opart = (float*)part;                // aliased (part consumed by
                                                 // k_combine before k_out writes)
    ushort* cat16 = (ushort*)(part + (size_t)512 * NCH * PSTRIDE32);  // 1081344 u16
    ushort* wbt16 = cat16 + 1081344;             // 2048 u16
    ushort* kfull = wbt16 + 2048;                // 512*352 u16
    ushort* woT   = kfull + 512 * KAW;           // 384*2112 u16
    ushort* vp2   = woT + (size_t)384 * 2112;    // 256*480*2 u16
    float*  out   = (float*)d_out;

    hipLaunchKernelGGL(k_prep, dim3(582), dim3(256), 0, stream,
                       Wq, Wk, Wv, Wqp, Wkp, Wvp, Wb, Wout, wcat, wbt16, woT);
    hipLaunchKernelGGL(k_gemm, dim3(24, 16), dim3(256), 0, stream,
                       s_i, wcat, rots, trans, P);
    hipLaunchKernelGGL(k_ka, dim3(512), dim3(128), 0, stream,
                       P, kfull, vp2);
    hipLaunchKernelGGL(k_flash, dim3(512, NCH), dim3(256), 0, stream,
                       z_ij, wbt16, gamma, P, kfull, vp2, part);
    hipLaunchKernelGGL(k_combine, dim3(512), dim3(256), 0, stream,
                       part, rots, trans, cat16);
    hipLaunchKernelGGL(k_out, dim3(16, 12, KS), dim3(256), 0, stream,
                       cat16, woT, opart);
    hipLaunchKernelGGL(k_outred, dim3(192), dim3(256), 0, stream,
                       opart, bout, out);
}

// Round 15
// 120.412 us; speedup vs baseline: 1.1669x; 1.0303x over previous
//
#include <hip/hip_runtime.h>
#include <hip/hip_bf16.h>
#include <math.h>

#define NRES 512
#define CS   384
#define CZ   128
#define NH   12
#define PW   1152   // packed projection width
#define JB   64     // j per flash block
#define NCH  8      // chunks = NRES/JB
#define PSTRIDE32 1040  // part chunk stride in u32 units
#define KS   6      // k_out K splits (2112 = 6*352)
#define KAW  352    // Kfull row width (11 * 32)

static constexpr float WL_F      = 0.57735026918962576f;   // sqrt(1/3)
static constexpr float HALF_WC_F = 0.11785113019775792f;   // 0.5*sqrt(2/(9*4))

typedef __attribute__((ext_vector_type(8))) short short8v;
typedef __attribute__((ext_vector_type(4))) float floatx4;

__device__ __forceinline__ ushort f2b(float f) {
    union { float f; uint u; } v; v.f = f;
    return (ushort)((v.u + 0x7FFFu + ((v.u >> 16) & 1u)) >> 16);
}
__device__ __forceinline__ float b2f(ushort b) {
    union { uint u; float f; } v; v.u = ((uint)b) << 16; return v.f;
}

// ---------------------------------------------------------------------------
// Kernel 0: prep. blocks [0,198): Wout -> WoutT16 bf16 transpose tiles
// (33 x 6); block 198: wbt16 (WbT bf16, scaled by W_L, rows >= 12 zero).
// ---------------------------------------------------------------------------
__global__ __launch_bounds__(256) void k_prep(
    const float* __restrict__ Wb, const float* __restrict__ Wout,
    ushort* __restrict__ wbt16, ushort* __restrict__ woT)
{
    __shared__ ushort tile[64][72];
    const int bx = blockIdx.x;
    if (bx < 198) {
        const int k0 = (bx % 33) * 64, c0 = (bx / 33) * 64;
        for (int idx = threadIdx.x; idx < 4096; idx += 256) {
            const int r = idx >> 6, c = idx & 63;
            tile[r][c] = f2b(Wout[(size_t)(k0 + r) * 384 + c0 + c]);
        }
        __syncthreads();
        for (int idx = threadIdx.x; idx < 4096; idx += 256) {
            const int c = idx >> 6, r = idx & 63;
            woT[(size_t)(c0 + c) * 2112 + k0 + r] = tile[r][c];
        }
    } else {
        for (int idx = threadIdx.x; idx < 16 * 128; idx += 256) {
            const int h = idx >> 7, cc = idx & 127;
            wbt16[idx] = (h < NH) ? f2b(WL_F * Wb[(size_t)cc * NH + h]) : (ushort)0;
        }
    }
}

// ---------------------------------------------------------------------------
// Kernel 1: P[512][1152] = s @ [Wq|Wk|Wv|Wqp|Wkp|Wvp], rigid transform fused
// for cols >= 576. B-tiles read DIRECTLY from the source weight matrix —
// every 48-col tile lies wholly inside one source (all boundaries % 48 == 0).
// ---------------------------------------------------------------------------
__global__ __launch_bounds__(256) void k_gemm(
    const float* __restrict__ s,
    const float* __restrict__ Wq, const float* __restrict__ Wk,
    const float* __restrict__ Wv, const float* __restrict__ Wqp,
    const float* __restrict__ Wkp, const float* __restrict__ Wvp,
    const float* __restrict__ rots, const float* __restrict__ trans,
    float* __restrict__ P)
{
    const int tid = threadIdx.x;
    const int tx = tid & 15, ty = tid >> 4;
    const int n0 = blockIdx.x * 48;
    const int m0 = blockIdx.y * 32;
    __shared__ float As[32][34];
    __shared__ float Bs[32][50];
    __shared__ float rot_lds[32][12];

    // block-uniform source select
    const float* Wsel; int W, base;
    if (n0 < 192)      { Wsel = Wq;  W = 192; base = 0;   }
    else if (n0 < 384) { Wsel = Wk;  W = 192; base = 192; }
    else if (n0 < 576) { Wsel = Wv;  W = 192; base = 384; }
    else if (n0 < 720) { Wsel = Wqp; W = 144; base = 576; }
    else if (n0 < 864) { Wsel = Wkp; W = 144; base = 720; }
    else               { Wsel = Wvp; W = 288; base = 864; }
    const int nb = n0 - base;

    if (n0 >= 576) {
        for (int idx = tid; idx < 32 * 12; idx += 256) {
            int r = idx / 12, q = idx % 12;
            rot_lds[r][q] = (q < 9) ? rots[(size_t)(m0 + r) * 9 + q]
                                    : trans[(size_t)(m0 + r) * 3 + q - 9];
        }
    }

    float acc[2][3];
    #pragma unroll
    for (int u = 0; u < 2; ++u)
        #pragma unroll
        for (int v = 0; v < 3; ++v) acc[u][v] = 0.f;

    for (int k0 = 0; k0 < CS; k0 += 32) {
        __syncthreads();
        #pragma unroll
        for (int l = 0; l < 4; ++l) {
            int idx = tid + l * 256;
            int kk = idx & 31, r = idx >> 5;
            As[kk][r] = s[(size_t)(m0 + r) * CS + k0 + kk];
        }
        #pragma unroll
        for (int l = 0; l < 6; ++l) {
            int idx = tid + l * 256;
            int kk = idx / 48, cc = idx % 48;
            Bs[kk][cc] = Wsel[(size_t)(k0 + kk) * W + nb + cc];
        }
        __syncthreads();
        #pragma unroll
        for (int kk = 0; kk < 32; ++kk) {
            const float2 a = *(const float2*)&As[kk][ty * 2];
            const float b0 = Bs[kk][tx * 3], b1 = Bs[kk][tx * 3 + 1], b2 = Bs[kk][tx * 3 + 2];
            acc[0][0] += a.x * b0; acc[0][1] += a.x * b1; acc[0][2] += a.x * b2;
            acc[1][0] += a.y * b0; acc[1][1] += a.y * b1; acc[1][2] += a.y * b2;
        }
    }

    #pragma unroll
    for (int u = 0; u < 2; ++u) {
        float v0 = acc[u][0], v1 = acc[u][1], v2 = acc[u][2];
        if (n0 >= 576) {
            const float* RT = rot_lds[ty * 2 + u];
            const float p0 = v0, p1 = v1, p2 = v2;
            v0 = RT[0] * p0 + RT[1] * p1 + RT[2] * p2 + RT[9];
            v1 = RT[3] * p0 + RT[4] * p1 + RT[5] * p2 + RT[10];
            v2 = RT[6] * p0 + RT[7] * p1 + RT[8] * p2 + RT[11];
        }
        float* dst = P + (size_t)(m0 + ty * 2 + u) * PW + n0 + tx * 3;
        dst[0] = v0; dst[1] = v1; dst[2] = v2;
    }
}

// ---------------------------------------------------------------------------
// Kernel 1b: Kfull[512][352] bf16 augmented K rows + vp2 packed V.
// Kfull: [0,192) k | [192,336) kg | [336,348) nj_h | 348: 1 | 349-351: 0
// vp2[p][c][par] bf16 (p=j/2, c in [0,480), par=j&1).
// ---------------------------------------------------------------------------
__global__ __launch_bounds__(128) void k_ka(
    const float* __restrict__ P, ushort* __restrict__ Kfull,
    ushort* __restrict__ vp2)
{
    const int j = blockIdx.x;
    const int tid = threadIdx.x;
    __shared__ float njs[NH];
    const float* prow = P + (size_t)j * PW;
    const float* kr  = prow + 192;
    const float* vr  = prow + 384;
    const float* kgr = prow + 720;
    const float* vgr = prow + 864;
    if (tid < NH) {
        float s = 0.f;
        #pragma unroll
        for (int e = 0; e < 12; ++e) { const float v = kgr[tid * 12 + e]; s += v * v; }
        njs[tid] = s;
    }
    __syncthreads();
    ushort* dst = Kfull + (size_t)j * KAW;
    for (int t = tid; t < KAW; t += 128) {
        float v;
        if (t < 192)       v = kr[t];
        else if (t < 336)  v = kgr[t - 192];
        else if (t < 348)  v = njs[t - 336];
        else if (t == 348) v = 1.0f;
        else               v = 0.f;
        dst[t] = f2b(v);
    }
    const int p = j >> 1, par = j & 1;
    for (int c = tid; c < 480; c += 128) {
        const float v = (c < 192) ? vr[c] : vgr[c - 192];
        vp2[((size_t)p * 480 + c) * 2 + par] = f2b(v);
    }
}

// ---------------------------------------------------------------------------
// Kernel 2: MFMA flash chunk. grid (512 i, 8 jc), 256 threads (4 waves).
// (byte-identical to R14 best: z once, LDS BfT build, 15-step logit MFMA,
// softmax, o_hat MFMA, vp2 phase E.)
// ---------------------------------------------------------------------------
__global__ __launch_bounds__(256, 6) void k_flash(
    const float* __restrict__ z, const ushort* __restrict__ wbt16,
    const float* __restrict__ gamma, const float* __restrict__ P,
    const ushort* __restrict__ Kfull, const ushort* __restrict__ vp2,
    uint* __restrict__ part)
{
    const int i   = blockIdx.x;
    const int jc  = blockIdx.y;
    const int j0  = jc * JB;
    const int tid = threadIdx.x;
    const int wid = tid >> 6, lane = tid & 63;

    __shared__ __align__(16) short zbT[128 * JB];    // 16384 B
    __shared__ __align__(16) char  uni[10240];       // BfT | {ltf, ltb, halfacc}
    __shared__ float pm[NH], ps[NH];

    short*  BfT     = (short*)uni;                   // [12][352] (logits phase)
    float*  ltf     = (float*)uni;                   // [16][68]  (after)
    short*  ltb     = (short*)(uni + 4352);          // [16][64]
    float4* halfacc = (float4*)(uni + 6400);         // [240]

    uint* pb32   = part + ((size_t)i * NCH + jc) * PSTRIDE32;
    ushort* pb16 = (ushort*)pb32;
    float* pbf   = (float*)pb32;

    const int jb = wid * 16 + (lane & 15);           // this thread's j row
    const int ko = (lane >> 4) * 8;                  // channel octet base

    // ---- phase A: z load (once) -> A-frags in regs + zbT scatter; BfT build ----
    short8v af[4];
    {
        const float* za = z + ((size_t)i * NRES + j0 + jb) * CZ + ko;
        #pragma unroll
        for (int m = 0; m < 4; ++m) {
            const float4 f0 = *(const float4*)(za + m * 32);
            const float4 f1 = *(const float4*)(za + m * 32 + 4);
            short8v a;
            a[0] = (short)f2b(f0.x); a[1] = (short)f2b(f0.y);
            a[2] = (short)f2b(f0.z); a[3] = (short)f2b(f0.w);
            a[4] = (short)f2b(f1.x); a[5] = (short)f2b(f1.y);
            a[6] = (short)f2b(f1.z); a[7] = (short)f2b(f1.w);
            af[m] = a;
            #pragma unroll
            for (int e = 0; e < 8; ++e) {
                const int c = ko + m * 32 + e;
                zbT[c * 64 + (((jb >> 3) ^ (c & 7)) * 8) + (jb & 7)] = a[e];
            }
        }
    }
    {
        const float* prow = P + (size_t)i * PW;
        for (int t = tid; t < 12 * 352; t += 256) {
            const int h = t / 352, k = t - h * 352;
            float v = 0.f;
            if (k < 192) {
                if ((k >> 4) == h) v = 0.25f * WL_F * prow[k];
            } else if (k < 336) {
                const int e = k - 192;
                if (e / 12 == h) v = 2.f * HALF_WC_F * WL_F * gamma[h] * prow[576 + e];
            } else if (k < 348) {
                if (k - 336 == h) v = -HALF_WC_F * WL_F * gamma[h];
            } else if (k == 348) {
                float ss = 0.f;
                #pragma unroll
                for (int e = 0; e < 12; ++e) {
                    const float x = prow[576 + h * 12 + e];
                    ss += x * x;
                }
                v = -HALF_WC_F * WL_F * gamma[h] * ss;
            }
            BfT[t] = (short)f2b(v);
        }
    }
    __syncthreads();

    // ---- phase B: fused logits MFMA (15 K-steps) ----
    floatx4 lacc = {0.f, 0.f, 0.f, 0.f};
    {
        const int n  = lane & 15;
        const int nb = (n < NH) ? n : 0;             // clamp garbage cols
        const ushort* arow = Kfull + (size_t)(j0 + jb) * KAW + ko;
        const short*  brow = &BfT[nb * 352 + ko];
        const ushort* wrow = wbt16 + n * 128 + ko;
        #pragma unroll
        for (int st = 0; st < 11; ++st) {
            const short8v a = *(const short8v*)(arow + st * 32);
            const short8v b = *(const short8v*)(brow + st * 32);
            lacc = __builtin_amdgcn_mfma_f32_16x16x32_bf16(a, b, lacc, 0, 0, 0);
        }
        #pragma unroll
        for (int st = 0; st < 4; ++st) {
            const short8v b = *(const short8v*)(wrow + st * 32);
            lacc = __builtin_amdgcn_mfma_f32_16x16x32_bf16(af[st], b, lacc, 0, 0, 0);
        }
    }
    __syncthreads();   // all waves done reading BfT
    {
        const int n = lane & 15;
        #pragma unroll
        for (int r = 0; r < 4; ++r)
            ltf[n * 68 + wid * 16 + (lane >> 4) * 4 + r] = lacc[r];
    }
    __syncthreads();

    // ---- phase C: chunk softmax (16 lanes/head) ----
    if (tid < 192) {
        const int h = tid >> 4, s = tid & 15;
        float4 v = *(const float4*)&ltf[h * 68 + s * 4];
        float m = fmaxf(fmaxf(v.x, v.y), fmaxf(v.z, v.w));
        #pragma unroll
        for (int o = 1; o < 16; o <<= 1) m = fmaxf(m, __shfl_xor(m, o));
        float4 e;
        e.x = __expf(v.x - m); e.y = __expf(v.y - m);
        e.z = __expf(v.z - m); e.w = __expf(v.w - m);
        float sum = e.x + e.y + e.z + e.w;
        #pragma unroll
        for (int o = 1; o < 16; o <<= 1) sum += __shfl_xor(sum, o);
        *(float4*)&ltf[h * 68 + s * 4] = e;
        const uint lo = (uint)f2b(e.x) | ((uint)f2b(e.y) << 16);
        const uint hi = (uint)f2b(e.z) | ((uint)f2b(e.w) << 16);
        uint* dst = (uint*)&ltb[h * 64 + (((s >> 1) ^ (h & 7)) * 8) + (s & 1) * 4];
        dst[0] = lo; dst[1] = hi;
        if (s == 0) { pm[h] = m; ps[h] = sum; }
    } else {
        const int tt = tid - 192;
        uint* dst = (uint*)&ltb[(12 + (tt >> 4)) * 64 + (tt & 15) * 4];
        dst[0] = 0u; dst[1] = 0u;
    }
    __syncthreads();

    // ---- phase D: o_hat MFMA — all 4 waves, 2 N-tiles each ----
    {
        const int hrow = lane & 15;
        const int u0 = (lane >> 4), u1 = u0 + 4;
        const short8v a0 = *(const short8v*)&ltb[hrow * 64 + ((u0 ^ (hrow & 7)) * 8)];
        const short8v a1 = *(const short8v*)&ltb[hrow * 64 + ((u1 ^ (hrow & 7)) * 8)];
        #pragma unroll
        for (int t = 0; t < 2; ++t) {
            const int d = (wid * 2 + t) * 16 + (lane & 15);
            const short8v b0 = *(const short8v*)&zbT[d * 64 + ((u0 ^ (d & 7)) * 8)];
            const short8v b1 = *(const short8v*)&zbT[d * 64 + ((u1 ^ (d & 7)) * 8)];
            floatx4 acc = {0.f, 0.f, 0.f, 0.f};
            acc = __builtin_amdgcn_mfma_f32_16x16x32_bf16(a0, b0, acc, 0, 0, 0);
            acc = __builtin_amdgcn_mfma_f32_16x16x32_bf16(a1, b1, acc, 0, 0, 0);
            #pragma unroll
            for (int r = 0; r < 4; ++r) {
                const int h = u0 * 4 + r;
                if (h < NH) pb16[h * 128 + d] = f2b(acc[r]);
            }
        }
    }

    // ---- phase E: o / o_hp — 240 slots, vp2 packed (2 j per 16B, coalesced) ----
    {
        if (tid < 240) {
            const int half = tid / 120, col = tid % 120;
            const int h = (col < 48) ? (col >> 2) : ((col - 48) / 6);
            const ushort* vb = vp2 + ((size_t)((j0 >> 1) + half * 16) * 480 + col * 4) * 2;
            const float* er = &ltf[h * 68 + half * 32];
            float ax = 0.f, ay = 0.f, az = 0.f, aw = 0.f;
            #pragma unroll 8
            for (int t = 0; t < 16; ++t) {
                const uint4 raw = *(const uint4*)(vb + (size_t)t * 960);
                const float e0 = er[2 * t], e1 = er[2 * t + 1];
                ax += e0 * b2f((ushort)raw.x) + e1 * b2f((ushort)(raw.x >> 16));
                ay += e0 * b2f((ushort)raw.y) + e1 * b2f((ushort)(raw.y >> 16));
                az += e0 * b2f((ushort)raw.z) + e1 * b2f((ushort)(raw.z >> 16));
                aw += e0 * b2f((ushort)raw.w) + e1 * b2f((ushort)(raw.w >> 16));
            }
            halfacc[tid] = make_float4(ax, ay, az, aw);
        }
        __syncthreads();
        if (tid < 120) {
            const float4 s0 = halfacc[tid], s1 = halfacc[tid + 120];
            const int off16 = (tid < 48) ? 1536 + tid * 4 : 1728 + (tid - 48) * 4;
            uint* dst = (uint*)&pb16[off16];
            dst[0] = (uint)f2b(s0.x + s1.x) | ((uint)f2b(s0.y + s1.y) << 16);
            dst[1] = (uint)f2b(s0.z + s1.z) | ((uint)f2b(s0.w + s1.w) << 16);
        }
        if (tid < NH) { pbf[1008 + tid] = pm[tid]; pbf[1020 + tid] = ps[tid]; }
    }
}

// ---------------------------------------------------------------------------
// Kernel 3: combine 8 chunks -> cat16 row (bf16). grid 512, 256 threads.
// ohat path vectorized: uint4 per thread per chunk (8 bf16).
// ---------------------------------------------------------------------------
__global__ __launch_bounds__(256) void k_combine(
    const uint* __restrict__ part, const float* __restrict__ rots,
    const float* __restrict__ trans, ushort* __restrict__ cat16)
{
    const int i   = blockIdx.x;
    const int tid = threadIdx.x;
    __shared__ float wgt[NCH][NH];
    __shared__ float ohp[288];

    const uint* base = part + (size_t)i * NCH * PSTRIDE32;
    if (tid < NH) {
        const int h = tid;
        float mm[NCH];
        float M = -1e30f;
        #pragma unroll
        for (int c = 0; c < NCH; ++c) {
            mm[c] = ((const float*)(base + c * PSTRIDE32))[1008 + h];
            M = fmaxf(M, mm[c]);
        }
        float S = 0.f;
        #pragma unroll
        for (int c = 0; c < NCH; ++c) {
            const float w = __expf(mm[c] - M);
            S += w * ((const float*)(base + c * PSTRIDE32))[1020 + h];
            wgt[c][h] = w;
        }
        const float inv = 1.0f / S;
        #pragma unroll
        for (int c = 0; c < NCH; ++c) wgt[c][h] *= inv;
    }
    __syncthreads();

    ushort* crow = cat16 + (size_t)i * 2112;
    uint*   crowu = (uint*)crow;
    if (tid < 192) {                                 // ohat: 192 thr x 8 bf16
        const int h = tid >> 4;
        float v[8];
        #pragma unroll
        for (int e = 0; e < 8; ++e) v[e] = 0.f;
        #pragma unroll
        for (int c = 0; c < NCH; ++c) {
            const uint4 u = *(const uint4*)&base[c * PSTRIDE32 + tid * 4];
            const float w = wgt[c][h];
            v[0] += b2f((ushort)u.x) * w; v[1] += b2f((ushort)(u.x >> 16)) * w;
            v[2] += b2f((ushort)u.y) * w; v[3] += b2f((ushort)(u.y >> 16)) * w;
            v[4] += b2f((ushort)u.z) * w; v[5] += b2f((ushort)(u.z >> 16)) * w;
            v[6] += b2f((ushort)u.w) * w; v[7] += b2f((ushort)(u.w >> 16)) * w;
        }
        uint4 o;
        o.x = (uint)f2b(v[0]) | ((uint)f2b(v[1]) << 16);
        o.y = (uint)f2b(v[2]) | ((uint)f2b(v[3]) << 16);
        o.z = (uint)f2b(v[4]) | ((uint)f2b(v[5]) << 16);
        o.w = (uint)f2b(v[6]) | ((uint)f2b(v[7]) << 16);
        *(uint4*)&crowu[tid * 4] = o;
    }
    if (tid < 96) {                                  // o: 192 bf16
        const int h = tid >> 3;
        float v0 = 0.f, v1 = 0.f;
        #pragma unroll
        for (int c = 0; c < NCH; ++c) {
            const uint u = base[c * PSTRIDE32 + 768 + tid];
            const float w = wgt[c][h];
            v0 += b2f((ushort)u) * w;
            v1 += b2f((ushort)(u >> 16)) * w;
        }
        crowu[768 + tid] = (uint)f2b(v0) | ((uint)f2b(v1) << 16);
    }
    if (tid < 144) {                                 // ohp: 288 vals
        const int h = tid / 12;
        float v0 = 0.f, v1 = 0.f;
        #pragma unroll
        for (int c = 0; c < NCH; ++c) {
            const uint u = base[c * PSTRIDE32 + 864 + tid];
            const float w = wgt[c][h];
            v0 += b2f((ushort)u) * w;
            v1 += b2f((ushort)(u >> 16)) * w;
        }
        ohp[tid * 2] = v0; ohp[tid * 2 + 1] = v1;
    }
    __syncthreads();

    if (tid < 96) {
        const int h = tid >> 3, p = tid & 7;
        float R[9];
        #pragma unroll
        for (int k = 0; k < 9; ++k) R[k] = rots[(size_t)i * 9 + k];
        const float g0 = ohp[h * 24 + p * 3 + 0] - trans[(size_t)i * 3 + 0];
        const float g1 = ohp[h * 24 + p * 3 + 1] - trans[(size_t)i * 3 + 1];
        const float g2 = ohp[h * 24 + p * 3 + 2] - trans[(size_t)i * 3 + 2];
        const float oy0 = R[0] * g0 + R[3] * g1 + R[6] * g2;
        const float oy1 = R[1] * g0 + R[4] * g1 + R[7] * g2;
        const float oy2 = R[2] * g0 + R[5] * g1 + R[8] * g2;
        crow[1728 + h * 24 + p * 3 + 0] = f2b(oy0);
        crow[1728 + h * 24 + p * 3 + 1] = f2b(oy1);
        crow[1728 + h * 24 + p * 3 + 2] = f2b(oy2);
        crow[2016 + h * 8 + p] = f2b(sqrtf(oy0 * oy0 + oy1 * oy1 + oy2 * oy2));
    }
}

// ---------------------------------------------------------------------------
// Kernel 4: out-proj MFMA. grid (16 m, 12 n, 6 k). 4 waves = 2x2 16x16 tiles.
// ---------------------------------------------------------------------------
__global__ __launch_bounds__(256) void k_out(
    const ushort* __restrict__ cat16, const ushort* __restrict__ woT,
    float* __restrict__ opart)
{
    const int tid = threadIdx.x;
    const int wid = tid >> 6, lane = tid & 63;
    const int wm = wid >> 1, wn = wid & 1;
    const int i0 = blockIdx.x * 32 + wm * 16;
    const int c0 = blockIdx.y * 32 + wn * 16;
    const int k0 = blockIdx.z * 352;
    const ushort* arow = cat16 + (size_t)(i0 + (lane & 15)) * 2112 + k0 + (lane >> 4) * 8;
    const ushort* brow = woT   + (size_t)(c0 + (lane & 15)) * 2112 + k0 + (lane >> 4) * 8;
    floatx4 acc = {0.f, 0.f, 0.f, 0.f};
    #pragma unroll
    for (int st = 0; st < 11; ++st) {
        const short8v a = *(const short8v*)(arow + st * 32);
        const short8v b = *(const short8v*)(brow + st * 32);
        acc = __builtin_amdgcn_mfma_f32_16x16x32_bf16(a, b, acc, 0, 0, 0);
    }
    float* ob = opart + (size_t)blockIdx.z * 512 * 384;
    #pragma unroll
    for (int r = 0; r < 4; ++r) {
        const int i = i0 + (lane >> 4) * 4 + r;
        ob[(size_t)i * 384 + c0 + (lane & 15)] = acc[r];
    }
}

// Kernel 5: reduce 6 k-partials + bias.
__global__ __launch_bounds__(256) void k_outred(
    const float* __restrict__ opart, const float* __restrict__ bout,
    float* __restrict__ out)
{
    const int e4 = blockIdx.x * 256 + threadIdx.x;
    const float4* p = (const float4*)opart;
    const float4 b = ((const float4*)bout)[e4 % 96];
    float4 r = b;
    #pragma unroll
    for (int k = 0; k < KS; ++k) {
        const float4 v = p[e4 + k * 49152];
        r.x += v.x; r.y += v.y; r.z += v.z; r.w += v.w;
    }
    ((float4*)out)[e4] = r;
}

// ---------------------------------------------------------------------------
extern "C" void kernel_launch(void* const* d_in, const int* in_sizes, int n_in,
                              void* d_out, int out_size, void* d_ws, size_t ws_size,
                              hipStream_t stream)
{
    const float* s_i   = (const float*)d_in[0];
    const float* z_ij  = (const float*)d_in[1];
    const float* rots  = (const float*)d_in[2];
    const float* trans = (const float*)d_in[3];
    const float* Wq    = (const float*)d_in[4];
    const float* Wk    = (const float*)d_in[5];
    const float* Wv    = (const float*)d_in[6];
    const float* Wqp   = (const float*)d_in[7];
    const float* Wkp   = (const float*)d_in[8];
    const float* Wvp   = (const float*)d_in[9];
    const float* Wb    = (const float*)d_in[10];
    const float* gamma = (const float*)d_in[11];
    const float* Wout  = (const float*)d_in[12];
    const float* bout  = (const float*)d_in[13];
    float* ws = (float*)d_ws;
    float*  P     = ws;                          // 589824 f
    uint*   part  = (uint*)(P + 589824);         // 512*8*1040 u32 (17 MB)
    float*  opart = (float*)part;                // aliased (part consumed by
                                                 // k_combine before k_out writes)
    ushort* cat16 = (ushort*)(part + (size_t)512 * NCH * PSTRIDE32);  // 1081344 u16
    ushort* wbt16 = cat16 + 1081344;             // 2048 u16
    ushort* kfull = wbt16 + 2048;                // 512*352 u16
    ushort* woT   = kfull + 512 * KAW;           // 384*2112 u16
    ushort* vp2   = woT + (size_t)384 * 2112;    // 256*480*2 u16
    float*  out   = (float*)d_out;

    hipLaunchKernelGGL(k_gemm, dim3(24, 16), dim3(256), 0, stream,
                       s_i, Wq, Wk, Wv, Wqp, Wkp, Wvp, rots, trans, P);
    hipLaunchKernelGGL(k_ka, dim3(512), dim3(128), 0, stream,
                       P, kfull, vp2);
    hipLaunchKernelGGL(k_prep, dim3(199), dim3(256), 0, stream,
                       Wb, Wout, wbt16, woT);
    hipLaunchKernelGGL(k_flash, dim3(512, NCH), dim3(256), 0, stream,
                       z_ij, wbt16, gamma, P, kfull, vp2, part);
    hipLaunchKernelGGL(k_combine, dim3(512), dim3(256), 0, stream,
                       part, rots, trans, cat16);
    hipLaunchKernelGGL(k_out, dim3(16, 12, KS), dim3(256), 0, stream,
                       cat16, woT, opart);
    hipLaunchKernelGGL(k_outred, dim3(192), dim3(256), 0, stream,
                       opart, bout, out);
}

// Round 16
// 116.156 us; speedup vs baseline: 1.2096x; 1.0366x over previous
//
#include <hip/hip_runtime.h>
#include <hip/hip_bf16.h>
#include <math.h>

#define NRES 512
#define CS   384
#define CZ   128
#define NH   12
#define PW   1152   // packed projection width
#define JB   64     // j per flash block
#define NCH  8      // chunks = NRES/JB
#define PSTRIDE32 1040  // part chunk stride in u32 units
#define KS   6      // k_out K splits (2112 = 6*352)
#define KAW  352    // Kfull row width (11 * 32)

static constexpr float WL_F      = 0.57735026918962576f;   // sqrt(1/3)
static constexpr float HALF_WC_F = 0.11785113019775792f;   // 0.5*sqrt(2/(9*4))

typedef __attribute__((ext_vector_type(8))) short short8v;
typedef __attribute__((ext_vector_type(4))) float floatx4;

__device__ __forceinline__ ushort f2b(float f) {
    union { float f; uint u; } v; v.f = f;
    return (ushort)((v.u + 0x7FFFu + ((v.u >> 16) & 1u)) >> 16);
}
__device__ __forceinline__ float b2f(ushort b) {
    union { uint u; float f; } v; v.u = ((uint)b) << 16; return v.f;
}

// ---------------------------------------------------------------------------
// Kernel 0: aux prep. blocks [0,512): Kfull + vp2 from P (per row);
// blocks [512,710): Wout -> WoutT16 transpose tiles; block 710: wbt16.
// ---------------------------------------------------------------------------
__global__ __launch_bounds__(256) void k_aux(
    const float* __restrict__ P, const float* __restrict__ Wb,
    const float* __restrict__ Wout,
    ushort* __restrict__ Kfull, ushort* __restrict__ vp2,
    ushort* __restrict__ wbt16, ushort* __restrict__ woT)
{
    __shared__ ushort tile[64][72];
    __shared__ float njs[NH];
    const int bx = blockIdx.x;
    const int tid = threadIdx.x;
    if (bx < 512) {
        const int j = bx;
        const float* prow = P + (size_t)j * PW;
        const float* kr  = prow + 192;
        const float* vr  = prow + 384;
        const float* kgr = prow + 720;
        const float* vgr = prow + 864;
        if (tid < NH) {
            float s = 0.f;
            #pragma unroll
            for (int e = 0; e < 12; ++e) { const float v = kgr[tid * 12 + e]; s += v * v; }
            njs[tid] = s;
        }
        __syncthreads();
        ushort* dst = Kfull + (size_t)j * KAW;
        for (int t = tid; t < KAW; t += 256) {
            float v;
            if (t < 192)       v = kr[t];
            else if (t < 336)  v = kgr[t - 192];
            else if (t < 348)  v = njs[t - 336];
            else if (t == 348) v = 1.0f;
            else               v = 0.f;
            dst[t] = f2b(v);
        }
        const int p = j >> 1, par = j & 1;
        for (int c = tid; c < 480; c += 256) {
            const float v = (c < 192) ? vr[c] : vgr[c - 192];
            vp2[((size_t)p * 480 + c) * 2 + par] = f2b(v);
        }
    } else if (bx < 710) {
        const int t = bx - 512;
        const int k0 = (t % 33) * 64, c0 = (t / 33) * 64;
        for (int idx = tid; idx < 4096; idx += 256) {
            const int r = idx >> 6, c = idx & 63;
            tile[r][c] = f2b(Wout[(size_t)(k0 + r) * 384 + c0 + c]);
        }
        __syncthreads();
        for (int idx = tid; idx < 4096; idx += 256) {
            const int c = idx >> 6, r = idx & 63;
            woT[(size_t)(c0 + c) * 2112 + k0 + r] = tile[r][c];
        }
    } else {
        for (int idx = tid; idx < 16 * 128; idx += 256) {
            const int h = idx >> 7, cc = idx & 127;
            wbt16[idx] = (h < NH) ? f2b(WL_F * Wb[(size_t)cc * NH + h]) : (ushort)0;
        }
    }
}

// ---------------------------------------------------------------------------
// Kernel 1: P[512][1152] = s @ [Wq|Wk|Wv|Wqp|Wkp|Wvp], rigid transform fused
// for cols >= 576. B-tiles read directly from source weights.
// ---------------------------------------------------------------------------
__global__ __launch_bounds__(256) void k_gemm(
    const float* __restrict__ s,
    const float* __restrict__ Wq, const float* __restrict__ Wk,
    const float* __restrict__ Wv, const float* __restrict__ Wqp,
    const float* __restrict__ Wkp, const float* __restrict__ Wvp,
    const float* __restrict__ rots, const float* __restrict__ trans,
    float* __restrict__ P)
{
    const int tid = threadIdx.x;
    const int tx = tid & 15, ty = tid >> 4;
    const int n0 = blockIdx.x * 48;
    const int m0 = blockIdx.y * 32;
    __shared__ float As[32][34];
    __shared__ float Bs[32][50];
    __shared__ float rot_lds[32][12];

    const float* Wsel; int W, base;
    if (n0 < 192)      { Wsel = Wq;  W = 192; base = 0;   }
    else if (n0 < 384) { Wsel = Wk;  W = 192; base = 192; }
    else if (n0 < 576) { Wsel = Wv;  W = 192; base = 384; }
    else if (n0 < 720) { Wsel = Wqp; W = 144; base = 576; }
    else if (n0 < 864) { Wsel = Wkp; W = 144; base = 720; }
    else               { Wsel = Wvp; W = 288; base = 864; }
    const int nb = n0 - base;

    if (n0 >= 576) {
        for (int idx = tid; idx < 32 * 12; idx += 256) {
            int r = idx / 12, q = idx % 12;
            rot_lds[r][q] = (q < 9) ? rots[(size_t)(m0 + r) * 9 + q]
                                    : trans[(size_t)(m0 + r) * 3 + q - 9];
        }
    }

    float acc[2][3];
    #pragma unroll
    for (int u = 0; u < 2; ++u)
        #pragma unroll
        for (int v = 0; v < 3; ++v) acc[u][v] = 0.f;

    for (int k0 = 0; k0 < CS; k0 += 32) {
        __syncthreads();
        #pragma unroll
        for (int l = 0; l < 4; ++l) {
            int idx = tid + l * 256;
            int kk = idx & 31, r = idx >> 5;
            As[kk][r] = s[(size_t)(m0 + r) * CS + k0 + kk];
        }
        #pragma unroll
        for (int l = 0; l < 6; ++l) {
            int idx = tid + l * 256;
            int kk = idx / 48, cc = idx % 48;
            Bs[kk][cc] = Wsel[(size_t)(k0 + kk) * W + nb + cc];
        }
        __syncthreads();
        #pragma unroll
        for (int kk = 0; kk < 32; ++kk) {
            const float2 a = *(const float2*)&As[kk][ty * 2];
            const float b0 = Bs[kk][tx * 3], b1 = Bs[kk][tx * 3 + 1], b2 = Bs[kk][tx * 3 + 2];
            acc[0][0] += a.x * b0; acc[0][1] += a.x * b1; acc[0][2] += a.x * b2;
            acc[1][0] += a.y * b0; acc[1][1] += a.y * b1; acc[1][2] += a.y * b2;
        }
    }

    #pragma unroll
    for (int u = 0; u < 2; ++u) {
        float v0 = acc[u][0], v1 = acc[u][1], v2 = acc[u][2];
        if (n0 >= 576) {
            const float* RT = rot_lds[ty * 2 + u];
            const float p0 = v0, p1 = v1, p2 = v2;
            v0 = RT[0] * p0 + RT[1] * p1 + RT[2] * p2 + RT[9];
            v1 = RT[3] * p0 + RT[4] * p1 + RT[5] * p2 + RT[10];
            v2 = RT[6] * p0 + RT[7] * p1 + RT[8] * p2 + RT[11];
        }
        float* dst = P + (size_t)(m0 + ty * 2 + u) * PW + n0 + tx * 3;
        dst[0] = v0; dst[1] = v1; dst[2] = v2;
    }
}

// ---------------------------------------------------------------------------
// Kernel 2: MFMA flash chunk. grid (512 i, 8 jc), 256 threads (4 waves).
// R15 structure + ILP surgery: __launch_bounds__(256,4) lifts the VGPR cap
// (40 -> ~128 budget) and explicit prefetch arrays batch the global loads
// (phase A: fz[8]; phase B: kf[11]+wv[4] BEFORE the MFMA chain; phase E:
// 2 batches of 8 vp2 loads) so loads overlap instead of load->use serial.
// ---------------------------------------------------------------------------
__global__ __launch_bounds__(256, 4) void k_flash(
    const float* __restrict__ z, const ushort* __restrict__ wbt16,
    const float* __restrict__ gamma, const float* __restrict__ P,
    const ushort* __restrict__ Kfull, const ushort* __restrict__ vp2,
    uint* __restrict__ part)
{
    const int i   = blockIdx.x;
    const int jc  = blockIdx.y;
    const int j0  = jc * JB;
    const int tid = threadIdx.x;
    const int wid = tid >> 6, lane = tid & 63;

    __shared__ __align__(16) short zbT[128 * JB];    // 16384 B
    __shared__ __align__(16) char  uni[10240];       // BfT | {ltf, ltb, halfacc}
    __shared__ float pm[NH], ps[NH];

    short*  BfT     = (short*)uni;                   // [12][352] (logits phase)
    float*  ltf     = (float*)uni;                   // [16][68]  (after)
    short*  ltb     = (short*)(uni + 4352);          // [16][64]
    float4* halfacc = (float4*)(uni + 6400);         // [240]

    uint* pb32   = part + ((size_t)i * NCH + jc) * PSTRIDE32;
    ushort* pb16 = (ushort*)pb32;
    float* pbf   = (float*)pb32;

    const int jb = wid * 16 + (lane & 15);           // this thread's j row
    const int ko = (lane >> 4) * 8;                  // channel octet base

    // ---- phase A: z load (batched) -> A-frags in regs + zbT scatter; BfT build ----
    short8v af[4];
    {
        const float* za = z + ((size_t)i * NRES + j0 + jb) * CZ + ko;
        float4 fz[8];
        #pragma unroll
        for (int m = 0; m < 4; ++m) {
            fz[2 * m]     = *(const float4*)(za + m * 32);
            fz[2 * m + 1] = *(const float4*)(za + m * 32 + 4);
        }
        #pragma unroll
        for (int m = 0; m < 4; ++m) {
            const float4 f0 = fz[2 * m], f1 = fz[2 * m + 1];
            short8v a;
            a[0] = (short)f2b(f0.x); a[1] = (short)f2b(f0.y);
            a[2] = (short)f2b(f0.z); a[3] = (short)f2b(f0.w);
            a[4] = (short)f2b(f1.x); a[5] = (short)f2b(f1.y);
            a[6] = (short)f2b(f1.z); a[7] = (short)f2b(f1.w);
            af[m] = a;
            #pragma unroll
            for (int e = 0; e < 8; ++e) {
                const int c = ko + m * 32 + e;
                zbT[c * 64 + (((jb >> 3) ^ (c & 7)) * 8) + (jb & 7)] = a[e];
            }
        }
    }
    {
        const float* prow = P + (size_t)i * PW;
        for (int t = tid; t < 12 * 352; t += 256) {
            const int h = t / 352, k = t - h * 352;
            float v = 0.f;
            if (k < 192) {
                if ((k >> 4) == h) v = 0.25f * WL_F * prow[k];
            } else if (k < 336) {
                const int e = k - 192;
                if (e / 12 == h) v = 2.f * HALF_WC_F * WL_F * gamma[h] * prow[576 + e];
            } else if (k < 348) {
                if (k - 336 == h) v = -HALF_WC_F * WL_F * gamma[h];
            } else if (k == 348) {
                float ss = 0.f;
                #pragma unroll
                for (int e = 0; e < 12; ++e) {
                    const float x = prow[576 + h * 12 + e];
                    ss += x * x;
                }
                v = -HALF_WC_F * WL_F * gamma[h] * ss;
            }
            BfT[t] = (short)f2b(v);
        }
    }
    __syncthreads();

    // ---- phase B: fused logits MFMA — prefetch all global frags, then chain ----
    floatx4 lacc = {0.f, 0.f, 0.f, 0.f};
    {
        const int n  = lane & 15;
        const int nb = (n < NH) ? n : 0;             // clamp garbage cols
        const ushort* arow = Kfull + (size_t)(j0 + jb) * KAW + ko;
        const short*  brow = &BfT[nb * 352 + ko];
        const ushort* wrow = wbt16 + n * 128 + ko;
        short8v kf[11], wv[4];
        #pragma unroll
        for (int st = 0; st < 11; ++st) kf[st] = *(const short8v*)(arow + st * 32);
        #pragma unroll
        for (int st = 0; st < 4; ++st)  wv[st] = *(const short8v*)(wrow + st * 32);
        #pragma unroll
        for (int st = 0; st < 11; ++st) {
            const short8v b = *(const short8v*)(brow + st * 32);
            lacc = __builtin_amdgcn_mfma_f32_16x16x32_bf16(kf[st], b, lacc, 0, 0, 0);
        }
        #pragma unroll
        for (int st = 0; st < 4; ++st)
            lacc = __builtin_amdgcn_mfma_f32_16x16x32_bf16(af[st], wv[st], lacc, 0, 0, 0);
    }
    __syncthreads();   // all waves done reading BfT
    {
        const int n = lane & 15;
        #pragma unroll
        for (int r = 0; r < 4; ++r)
            ltf[n * 68 + wid * 16 + (lane >> 4) * 4 + r] = lacc[r];
    }
    __syncthreads();

    // ---- phase C: chunk softmax (16 lanes/head) ----
    if (tid < 192) {
        const int h = tid >> 4, s = tid & 15;
        float4 v = *(const float4*)&ltf[h * 68 + s * 4];
        float m = fmaxf(fmaxf(v.x, v.y), fmaxf(v.z, v.w));
        #pragma unroll
        for (int o = 1; o < 16; o <<= 1) m = fmaxf(m, __shfl_xor(m, o));
        float4 e;
        e.x = __expf(v.x - m); e.y = __expf(v.y - m);
        e.z = __expf(v.z - m); e.w = __expf(v.w - m);
        float sum = e.x + e.y + e.z + e.w;
        #pragma unroll
        for (int o = 1; o < 16; o <<= 1) sum += __shfl_xor(sum, o);
        *(float4*)&ltf[h * 68 + s * 4] = e;
        const uint lo = (uint)f2b(e.x) | ((uint)f2b(e.y) << 16);
        const uint hi = (uint)f2b(e.z) | ((uint)f2b(e.w) << 16);
        uint* dst = (uint*)&ltb[h * 64 + (((s >> 1) ^ (h & 7)) * 8) + (s & 1) * 4];
        dst[0] = lo; dst[1] = hi;
        if (s == 0) { pm[h] = m; ps[h] = sum; }
    } else {
        const int tt = tid - 192;
        uint* dst = (uint*)&ltb[(12 + (tt >> 4)) * 64 + (tt & 15) * 4];
        dst[0] = 0u; dst[1] = 0u;
    }
    __syncthreads();

    // ---- phase D: o_hat MFMA — all 4 waves, 2 N-tiles each ----
    {
        const int hrow = lane & 15;
        const int u0 = (lane >> 4), u1 = u0 + 4;
        const short8v a0 = *(const short8v*)&ltb[hrow * 64 + ((u0 ^ (hrow & 7)) * 8)];
        const short8v a1 = *(const short8v*)&ltb[hrow * 64 + ((u1 ^ (hrow & 7)) * 8)];
        #pragma unroll
        for (int t = 0; t < 2; ++t) {
            const int d = (wid * 2 + t) * 16 + (lane & 15);
            const short8v b0 = *(const short8v*)&zbT[d * 64 + ((u0 ^ (d & 7)) * 8)];
            const short8v b1 = *(const short8v*)&zbT[d * 64 + ((u1 ^ (d & 7)) * 8)];
            floatx4 acc = {0.f, 0.f, 0.f, 0.f};
            acc = __builtin_amdgcn_mfma_f32_16x16x32_bf16(a0, b0, acc, 0, 0, 0);
            acc = __builtin_amdgcn_mfma_f32_16x16x32_bf16(a1, b1, acc, 0, 0, 0);
            #pragma unroll
            for (int r = 0; r < 4; ++r) {
                const int h = u0 * 4 + r;
                if (h < NH) pb16[h * 128 + d] = f2b(acc[r]);
            }
        }
    }

    // ---- phase E: o / o_hp — 240 slots, vp2 packed, 2 batches of 8 loads ----
    {
        if (tid < 240) {
            const int half = tid / 120, col = tid % 120;
            const int h = (col < 48) ? (col >> 2) : ((col - 48) / 6);
            const ushort* vb = vp2 + ((size_t)((j0 >> 1) + half * 16) * 480 + col * 4) * 2;
            const float* er = &ltf[h * 68 + half * 32];
            float ax = 0.f, ay = 0.f, az = 0.f, aw = 0.f;
            #pragma unroll
            for (int b = 0; b < 2; ++b) {
                uint4 raw[8];
                #pragma unroll
                for (int t = 0; t < 8; ++t)
                    raw[t] = *(const uint4*)(vb + (size_t)(b * 8 + t) * 960);
                #pragma unroll
                for (int t = 0; t < 8; ++t) {
                    const float e0 = er[2 * (b * 8 + t)], e1 = er[2 * (b * 8 + t) + 1];
                    ax += e0 * b2f((ushort)raw[t].x) + e1 * b2f((ushort)(raw[t].x >> 16));
                    ay += e0 * b2f((ushort)raw[t].y) + e1 * b2f((ushort)(raw[t].y >> 16));
                    az += e0 * b2f((ushort)raw[t].z) + e1 * b2f((ushort)(raw[t].z >> 16));
                    aw += e0 * b2f((ushort)raw[t].w) + e1 * b2f((ushort)(raw[t].w >> 16));
                }
            }
            halfacc[tid] = make_float4(ax, ay, az, aw);
        }
        __syncthreads();
        if (tid < 120) {
            const float4 s0 = halfacc[tid], s1 = halfacc[tid + 120];
            const int off16 = (tid < 48) ? 1536 + tid * 4 : 1728 + (tid - 48) * 4;
            uint* dst = (uint*)&pb16[off16];
            dst[0] = (uint)f2b(s0.x + s1.x) | ((uint)f2b(s0.y + s1.y) << 16);
            dst[1] = (uint)f2b(s0.z + s1.z) | ((uint)f2b(s0.w + s1.w) << 16);
        }
        if (tid < NH) { pbf[1008 + tid] = pm[tid]; pbf[1020 + tid] = ps[tid]; }
    }
}

// ---------------------------------------------------------------------------
// Kernel 3: combine 8 chunks -> cat16 row (bf16). grid 512, 256 threads.
// ---------------------------------------------------------------------------
__global__ __launch_bounds__(256) void k_combine(
    const uint* __restrict__ part, const float* __restrict__ rots,
    const float* __restrict__ trans, ushort* __restrict__ cat16)
{
    const int i   = blockIdx.x;
    const int tid = threadIdx.x;
    __shared__ float wgt[NCH][NH];
    __shared__ float ohp[288];

    const uint* base = part + (size_t)i * NCH * PSTRIDE32;
    if (tid < NH) {
        const int h = tid;
        float mm[NCH];
        float M = -1e30f;
        #pragma unroll
        for (int c = 0; c < NCH; ++c) {
            mm[c] = ((const float*)(base + c * PSTRIDE32))[1008 + h];
            M = fmaxf(M, mm[c]);
        }
        float S = 0.f;
        #pragma unroll
        for (int c = 0; c < NCH; ++c) {
            const float w = __expf(mm[c] - M);
            S += w * ((const float*)(base + c * PSTRIDE32))[1020 + h];
            wgt[c][h] = w;
        }
        const float inv = 1.0f / S;
        #pragma unroll
        for (int c = 0; c < NCH; ++c) wgt[c][h] *= inv;
    }
    __syncthreads();

    ushort* crow = cat16 + (size_t)i * 2112;
    uint*   crowu = (uint*)crow;
    if (tid < 192) {
        const int h = tid >> 4;
        float v[8];
        #pragma unroll
        for (int e = 0; e < 8; ++e) v[e] = 0.f;
        #pragma unroll
        for (int c = 0; c < NCH; ++c) {
            const uint4 u = *(const uint4*)&base[c * PSTRIDE32 + tid * 4];
            const float w = wgt[c][h];
            v[0] += b2f((ushort)u.x) * w; v[1] += b2f((ushort)(u.x >> 16)) * w;
            v[2] += b2f((ushort)u.y) * w; v[3] += b2f((ushort)(u.y >> 16)) * w;
            v[4] += b2f((ushort)u.z) * w; v[5] += b2f((ushort)(u.z >> 16)) * w;
            v[6] += b2f((ushort)u.w) * w; v[7] += b2f((ushort)(u.w >> 16)) * w;
        }
        uint4 o;
        o.x = (uint)f2b(v[0]) | ((uint)f2b(v[1]) << 16);
        o.y = (uint)f2b(v[2]) | ((uint)f2b(v[3]) << 16);
        o.z = (uint)f2b(v[4]) | ((uint)f2b(v[5]) << 16);
        o.w = (uint)f2b(v[6]) | ((uint)f2b(v[7]) << 16);
        *(uint4*)&crowu[tid * 4] = o;
    }
    if (tid < 96) {
        const int h = tid >> 3;
        float v0 = 0.f, v1 = 0.f;
        #pragma unroll
        for (int c = 0; c < NCH; ++c) {
            const uint u = base[c * PSTRIDE32 + 768 + tid];
            const float w = wgt[c][h];
            v0 += b2f((ushort)u) * w;
            v1 += b2f((ushort)(u >> 16)) * w;
        }
        crowu[768 + tid] = (uint)f2b(v0) | ((uint)f2b(v1) << 16);
    }
    if (tid < 144) {
        const int h = tid / 12;
        float v0 = 0.f, v1 = 0.f;
        #pragma unroll
        for (int c = 0; c < NCH; ++c) {
            const uint u = base[c * PSTRIDE32 + 864 + tid];
            const float w = wgt[c][h];
            v0 += b2f((ushort)u) * w;
            v1 += b2f((ushort)(u >> 16)) * w;
        }
        ohp[tid * 2] = v0; ohp[tid * 2 + 1] = v1;
    }
    __syncthreads();

    if (tid < 96) {
        const int h = tid >> 3, p = tid & 7;
        float R[9];
        #pragma unroll
        for (int k = 0; k < 9; ++k) R[k] = rots[(size_t)i * 9 + k];
        const float g0 = ohp[h * 24 + p * 3 + 0] - trans[(size_t)i * 3 + 0];
        const float g1 = ohp[h * 24 + p * 3 + 1] - trans[(size_t)i * 3 + 1];
        const float g2 = ohp[h * 24 + p * 3 + 2] - trans[(size_t)i * 3 + 2];
        const float oy0 = R[0] * g0 + R[3] * g1 + R[6] * g2;
        const float oy1 = R[1] * g0 + R[4] * g1 + R[7] * g2;
        const float oy2 = R[2] * g0 + R[5] * g1 + R[8] * g2;
        crow[1728 + h * 24 + p * 3 + 0] = f2b(oy0);
        crow[1728 + h * 24 + p * 3 + 1] = f2b(oy1);
        crow[1728 + h * 24 + p * 3 + 2] = f2b(oy2);
        crow[2016 + h * 8 + p] = f2b(sqrtf(oy0 * oy0 + oy1 * oy1 + oy2 * oy2));
    }
}

// ---------------------------------------------------------------------------
// Kernel 4: out-proj MFMA. grid (16 m, 12 n, 6 k). 4 waves = 2x2 16x16 tiles.
// ---------------------------------------------------------------------------
__global__ __launch_bounds__(256) void k_out(
    const ushort* __restrict__ cat16, const ushort* __restrict__ woT,
    float* __restrict__ opart)
{
    const int tid = threadIdx.x;
    const int wid = tid >> 6, lane = tid & 63;
    const int wm = wid >> 1, wn = wid & 1;
    const int i0 = blockIdx.x * 32 + wm * 16;
    const int c0 = blockIdx.y * 32 + wn * 16;
    const int k0 = blockIdx.z * 352;
    const ushort* arow = cat16 + (size_t)(i0 + (lane & 15)) * 2112 + k0 + (lane >> 4) * 8;
    const ushort* brow = woT   + (size_t)(c0 + (lane & 15)) * 2112 + k0 + (lane >> 4) * 8;
    floatx4 acc = {0.f, 0.f, 0.f, 0.f};
    #pragma unroll
    for (int st = 0; st < 11; ++st) {
        const short8v a = *(const short8v*)(arow + st * 32);
        const short8v b = *(const short8v*)(brow + st * 32);
        acc = __builtin_amdgcn_mfma_f32_16x16x32_bf16(a, b, acc, 0, 0, 0);
    }
    float* ob = opart + (size_t)blockIdx.z * 512 * 384;
    #pragma unroll
    for (int r = 0; r < 4; ++r) {
        const int i = i0 + (lane >> 4) * 4 + r;
        ob[(size_t)i * 384 + c0 + (lane & 15)] = acc[r];
    }
}

// Kernel 5: reduce 6 k-partials + bias.
__global__ __launch_bounds__(256) void k_outred(
    const float* __restrict__ opart, const float* __restrict__ bout,
    float* __restrict__ out)
{
    const int e4 = blockIdx.x * 256 + threadIdx.x;
    const float4* p = (const float4*)opart;
    const float4 b = ((const float4*)bout)[e4 % 96];
    float4 r = b;
    #pragma unroll
    for (int k = 0; k < KS; ++k) {
        const float4 v = p[e4 + k * 49152];
        r.x += v.x; r.y += v.y; r.z += v.z; r.w += v.w;
    }
    ((float4*)out)[e4] = r;
}

// ---------------------------------------------------------------------------
extern "C" void kernel_launch(void* const* d_in, const int* in_sizes, int n_in,
                              void* d_out, int out_size, void* d_ws, size_t ws_size,
                              hipStream_t stream)
{
    const float* s_i   = (const float*)d_in[0];
    const float* z_ij  = (const float*)d_in[1];
    const float* rots  = (const float*)d_in[2];
    const float* trans = (const float*)d_in[3];
    const float* Wq    = (const float*)d_in[4];
    const float* Wk    = (const float*)d_in[5];
    const float* Wv    = (const float*)d_in[6];
    const float* Wqp   = (const float*)d_in[7];
    const float* Wkp   = (const float*)d_in[8];
    const float* Wvp   = (const float*)d_in[9];
    const float* Wb    = (const float*)d_in[10];
    const float* gamma = (const float*)d_in[11];
    const float* Wout  = (const float*)d_in[12];
    const float* bout  = (const float*)d_in[13];
    float* ws = (float*)d_ws;
    float*  P     = ws;                          // 589824 f
    uint*   part  = (uint*)(P + 589824);         // 512*8*1040 u32 (17 MB)
    float*  opart = (float*)part;                // aliased (part consumed by
                                                 // k_combine before k_out writes)
    ushort* cat16 = (ushort*)(part + (size_t)512 * NCH * PSTRIDE32);  // 1081344 u16
    ushort* wbt16 = cat16 + 1081344;             // 2048 u16
    ushort* kfull = wbt16 + 2048;                // 512*352 u16
    ushort* woT   = kfull + 512 * KAW;           // 384*2112 u16
    ushort* vp2   = woT + (size_t)384 * 2112;    // 256*480*2 u16
    float*  out   = (float*)d_out;

    hipLaunchKernelGGL(k_gemm, dim3(24, 16), dim3(256), 0, stream,
                       s_i, Wq, Wk, Wv, Wqp, Wkp, Wvp, rots, trans, P);
    hipLaunchKernelGGL(k_aux, dim3(711), dim3(256), 0, stream,
                       P, Wb, Wout, kfull, vp2, wbt16, woT);
    hipLaunchKernelGGL(k_flash, dim3(512, NCH), dim3(256), 0, stream,
                       z_ij, wbt16, gamma, P, kfull, vp2, part);
    hipLaunchKernelGGL(k_combine, dim3(512), dim3(256), 0, stream,
                       part, rots, trans, cat16);
    hipLaunchKernelGGL(k_out, dim3(16, 12, KS), dim3(256), 0, stream,
                       cat16, woT, opart);
    hipLaunchKernelGGL(k_outred, dim3(192), dim3(256), 0, stream,
                       opart, bout, out);
}